// Round 8
// baseline (256.174 us; speedup 1.0000x reference)
//
#include <hip/hip_runtime.h>

typedef __attribute__((ext_vector_type(8))) short short8;
typedef __attribute__((ext_vector_type(4))) float f32x4;

#define DIM 1024
#define NH 16
#define HD 64
#define LAT 128
#define QR 256
#define NCAT (LAT + QR) /* 384 */
#define BB 4
#define SS 2048
#define BS (BB * SS) /* 8192 */

// exp(s*0.125) == exp2(s * 0.125*log2(e)); baked into Q at the GEMM epilogue.
#define SCALE_LOG2E 0.18033688011112042f

__device__ __forceinline__ unsigned short f2b(float f) {
  unsigned int u = __builtin_bit_cast(unsigned int, f);
  u += 0x7FFFu + ((u >> 16) & 1u); // RNE
  return (unsigned short)(u >> 16);
}
__device__ __forceinline__ float b2f(unsigned short h) {
  unsigned int u = ((unsigned int)h) << 16;
  return __builtin_bit_cast(float, u);
}
// pack hi16(f0)|hi16(f1)<<16 with round-half-up (safe: inputs >= 0, no NaN)
__device__ __forceinline__ unsigned int pack_bf16_pair(float f0, float f1) {
  unsigned int u0 = __builtin_bit_cast(unsigned int, f0) + 0x8000u;
  unsigned int u1 = __builtin_bit_cast(unsigned int, f1) + 0x8000u;
  return __builtin_amdgcn_perm(u1, u0, 0x07060302u);
}
// async global->LDS, 16B per lane. LDS dest is wave-uniform base + lane*16.
__device__ __forceinline__ void gll16(const unsigned short* g, unsigned short* l) {
  __builtin_amdgcn_global_load_lds(
      (const __attribute__((address_space(1))) unsigned int*)g,
      (__attribute__((address_space(3))) unsigned int*)l, 16, 0, 0);
}

__global__ __launch_bounds__(256) void cvt_x(const float* __restrict__ in,
                                             unsigned short* __restrict__ out, int n4) {
  int i = blockIdx.x * 256 + threadIdx.x;
  if (i >= n4) return;
  f32x4 v = ((const f32x4*)in)[i];
  ushort4 o;
  o.x = f2b(v[0]); o.y = f2b(v[1]); o.z = f2b(v[2]); o.w = f2b(v[3]);
  ((ushort4*)out)[i] = o;
}

// Fused prep: all 5 weight transposes (f32 [K][N] -> bf16 [N][K], 64x64 LDS
// tiles) + bias concat, one launch.
__global__ __launch_bounds__(256) void prep_weights(
    const float* __restrict__ w_kvc, const float* __restrict__ w_qc,
    const float* __restrict__ w_kvu, const float* __restrict__ w_qu,
    const float* __restrict__ w_o, const float* __restrict__ b_kvc,
    const float* __restrict__ b_qc, unsigned short* __restrict__ wcatT,
    unsigned short* __restrict__ wkvuT, unsigned short* __restrict__ wquT,
    unsigned short* __restrict__ woT, float* __restrict__ bias_cat) {
  __shared__ unsigned short T[64 * 72];
  const int id = blockIdx.x;
  const int tid = threadIdx.x;
  if (id >= 480) { // bias concat (384 floats)
    if (tid < LAT) bias_cat[tid] = b_kvc[tid];
    else bias_cat[tid] = b_qc[tid - LAT];
    if (tid < 128) bias_cat[tid + 256] = b_qc[tid + 128];
    return;
  }
  const float* in; unsigned short* out; int K, N, tile;
  if (id < 32)       { in = w_kvc; out = wcatT;                       K = DIM; N = LAT;     tile = id; }
  else if (id < 96)  { in = w_qc;  out = wcatT + (size_t)LAT * DIM;   K = DIM; N = QR;      tile = id - 32; }
  else if (id < 160) { in = w_kvu; out = wkvuT;                       K = LAT; N = 2 * DIM; tile = id - 96; }
  else if (id < 224) { in = w_qu;  out = wquT;                        K = QR;  N = DIM;     tile = id - 160; }
  else               { in = w_o;   out = woT;                         K = DIM; N = DIM;     tile = id - 224; }
  const int ktiles = K >> 6;
  const int k0 = (tile % ktiles) * 64, n0 = (tile / ktiles) * 64;
  {
    const int r = tid >> 2, cq = (tid & 3) * 16;
#pragma unroll
    for (int j = 0; j < 4; ++j) {
      f32x4 v = *(const f32x4*)(in + (size_t)(k0 + r) * N + n0 + cq + j * 4);
      ushort4 o;
      o.x = f2b(v[0]); o.y = f2b(v[1]); o.z = f2b(v[2]); o.w = f2b(v[3]);
      *(ushort4*)(T + r * 72 + cq + j * 4) = o;
    }
  }
  __syncthreads();
#pragma unroll
  for (int s = 0; s < 2; ++s) {
    int idx = tid + s * 256;
    int nr = idx >> 3, kg = (idx & 7) * 8;
    short8 o;
#pragma unroll
    for (int i = 0; i < 8; i++) o[i] = T[(kg + i) * 72 + nr];
    *(short8*)(out + (size_t)(n0 + nr) * K + k0 + kg) = o;
  }
}

// LDS-staged GEMM, 4-deep counted-vmcnt pipeline (T3+T4 recipe):
// C[M,N] = (A[M,K]@WT[N,K] + bias)*scale. BM=BN=128, BK=32, 256 thr =
// 4 waves, 64x64/wave. 4-buffer ring; 12 staging loads in flight; per
// iteration: vmcnt(counted 8/4/0) -> lgkmcnt(0) -> raw s_barrier ->
// issue STAGE(t+3) -> ds_read+MFMA. The counted wait precedes the barrier
// so ALL waves' stage-t tiles are complete for all readers; the barrier
// protects the buffer being overwritten (read at t-1). Bank-conflict fix
// per rule #21 (global_load_lds writes linearly): pre-swizzle the per-lane
// GLOBAL source col-group (cg ^= row&3), read with the same XOR -> 16-way
// conflicts down to 4-way. LDS 64 KB -> 2 blocks/CU. XCD-chunked swizzle.
// vtOut: blocks with n0 >= DIM write tile transposed (fused V-transpose).
__global__ __launch_bounds__(256, 2) void gemm_lds(const unsigned short* __restrict__ A,
                                                   const unsigned short* __restrict__ WT,
                                                   const float* __restrict__ bias,
                                                   float* __restrict__ outF,
                                                   unsigned short* __restrict__ outB,
                                                   unsigned short* __restrict__ vtOut,
                                                   int N, int K, int lda, int ldout,
                                                   float scale, int nblk) {
  __shared__ unsigned short gsm[32768]; // A ring 4x4096 | B ring 4x4096 (shorts)
  const int tid = threadIdx.x;
  const int wave = tid >> 6, lane = tid & 63;
  const int ln = lane & 15, quad = lane >> 4;
  const int chunk = nblk >> 3;
  const int sw = (blockIdx.x & 7) * chunk + (blockIdx.x >> 3);
  const int nwx = N >> 7;
  const int bx = sw % nwx, by = sw / nwx;
  const int m0 = by * 128, n0 = bx * 128;
  const int wm = (wave >> 1) * 64, wn = (wave & 1) * 64;

  // staging: wave w stages rows w*32..w*32+31 in 2 shots of 16 rows.
  // lane: row = lane>>2, colgroup = lane&3 (8 shorts each); global source
  // col pre-swizzled cg^(row&3); LDS dest linear (lane*16B).
  const int sr = lane >> 2;
  const int scg = (lane & 3) ^ (sr & 3);
  const unsigned short* Ag = A + (size_t)(m0 + wave * 32 + sr) * lda + scg * 8;
  const unsigned short* Bg = WT + (size_t)(n0 + wave * 32 + sr) * K + scg * 8;

  f32x4 acc[4][4];
#pragma unroll
  for (int i = 0; i < 4; i++)
#pragma unroll
    for (int j = 0; j < 4; j++) acc[i][j] = (f32x4){0.f, 0.f, 0.f, 0.f};

#define STAGE(buf, kk)                                                        \
  {                                                                           \
    unsigned short* Al = gsm + (buf) * 4096 + wave * 1024;                    \
    unsigned short* Bl = gsm + 16384 + (buf) * 4096 + wave * 1024;            \
    gll16(Ag + (kk), Al);                                                     \
    gll16(Ag + (size_t)16 * lda + (kk), Al + 512);                            \
    gll16(Bg + (kk), Bl);                                                     \
    gll16(Bg + (size_t)16 * K + (kk), Bl + 512);                              \
  }

  const int T = K >> 5; // >= 4 at all call sites
  STAGE(0, 0);
  STAGE(1, 32);
  STAGE(2, 64);

  const int rc = (quad ^ (ln & 3)) * 8; // swizzled fragment col (shorts)
  for (int t = 0; t < T; ++t) {
    const int rem = T - 1 - t;
    if (rem >= 2)      asm volatile("s_waitcnt vmcnt(8)" ::: "memory");
    else if (rem == 1) asm volatile("s_waitcnt vmcnt(4)" ::: "memory");
    else               asm volatile("s_waitcnt vmcnt(0)" ::: "memory");
    asm volatile("s_waitcnt lgkmcnt(0)" ::: "memory"); // prior reads consumed
    __builtin_amdgcn_s_barrier();
    if (t + 3 < T) STAGE((t + 3) & 3, (t + 3) * 32);
    const unsigned short* Ab = gsm + (t & 3) * 4096;
    const unsigned short* Bb = gsm + 16384 + (t & 3) * 4096;
    short8 af[4], bf[4];
#pragma unroll
    for (int i = 0; i < 4; i++) {
      af[i] = *(const short8*)(Ab + (wm + i * 16 + ln) * 32 + rc);
      bf[i] = *(const short8*)(Bb + (wn + i * 16 + ln) * 32 + rc);
    }
#pragma unroll
    for (int mi = 0; mi < 4; mi++)
#pragma unroll
      for (int ni = 0; ni < 4; ni++)
        acc[mi][ni] =
            __builtin_amdgcn_mfma_f32_16x16x32_bf16(af[mi], bf[ni], acc[mi][ni], 0, 0, 0);
  }
#undef STAGE

  if (vtOut && n0 >= DIM) {
    // Fused V-transpose path: stage tile transposed in LDS, write VT rows.
    __syncthreads(); // all waves done reading the ring
#pragma unroll
    for (int mi = 0; mi < 4; mi++) {
      const int s = wm + mi * 16 + quad * 4;
#pragma unroll
      for (int ni = 0; ni < 4; ni++) {
        const int d = wn + ni * 16 + ln;
        const float bv = bias[n0 + d];
#pragma unroll
        for (int r = 0; r < 4; r++)
          gsm[d * 136 + s + r] = f2b(acc[mi][ni][r] + bv);
      }
    }
    __syncthreads();
    const int d0 = n0 - DIM, bb = m0 >> 11, s0l = m0 & (SS - 1);
#pragma unroll
    for (int t = 0; t < 8; ++t) {
      int idx = tid + t * 256;
      int dr = idx >> 4, cs = (idx & 15) * 8;
      short8 v = *(const short8*)(gsm + dr * 136 + cs);
      *(short8*)(vtOut + (size_t)(bb * DIM + d0 + dr) * SS + s0l + cs) = v;
    }
    return;
  }

#pragma unroll
  for (int mi = 0; mi < 4; mi++) {
    const int row = m0 + wm + mi * 16 + quad * 4;
#pragma unroll
    for (int ni = 0; ni < 4; ni++) {
      const int col = n0 + wn + ni * 16 + ln;
      const float bv = bias[col];
#pragma unroll
      for (int r = 0; r < 4; r++) {
        float v = (acc[mi][ni][r] + bv) * scale;
        size_t o = (size_t)(row + r) * ldout + col;
        if (outF) outF[o] = v;
        if (outB) outB[o] = f2b(v);
      }
    }
  }
}

// MFMA flash attention, causal, fixed-max softmax, S^T orientation.
// FROZEN (measured 80.5 us): sequential streams, antidiagonal pairing
// (tA=pair, tB=31-pair; uniform 33 units), 1024 blocks = 4/CU,
// XCD-affinity decode (K/V L2-resident, FETCH ~25 MB), XOR swizzle
// (conflicts 2.2e6).
__global__ __launch_bounds__(256, 4) void attn_mfma(const unsigned short* __restrict__ Qb,
                                                    const unsigned short* __restrict__ KVb,
                                                    const unsigned short* __restrict__ VTb,
                                                    unsigned short* __restrict__ ctxB) {
  __shared__ unsigned short smem[12288]; // 24576 B
  unsigned short* Ks = smem;             // [64 key][64 d] swz
  unsigned short* Vts = smem + 4096;     // [64 d][64 key] swz
  unsigned short* Ps = smem + 8192;      // 4 waves x [16 q][64 key] swz
  const int tid = threadIdx.x;
  const int wave = tid >> 6, lane = tid & 63;
  const int ln = lane & 15, quad = lane >> 4;
  // XCD-affinity decode (all 16 pair-blocks of one (b,h) on one XCD)
  const int hw = blockIdx.x;              // 0..1023
  const int xcd = hw & 7, slot = hw >> 3; // slot 0..127
  const int grp = xcd * 8 + (slot >> 4);  // 0..63 = (b,h) group
  const int pair = slot & 15;             // 0..15
  const int h = grp & 15, b = grp >> 4;
  const int tA = pair, tB = 31 - pair;    // 64-row q-tile indices, tB > tA
  const int s0A = tA * 64, s0B = tB * 64;
  const int ktmaxB = tB;                  // inclusive
  const int qminA = s0A + wave * 16, qmaxA = qminA + 15;
  const int qminB = s0B + wave * 16, qmaxB = qminB + 15;

  short8 qfA[2], qfB[2]; // B-operand: rows = q
  {
    const unsigned short* qa =
        Qb + (size_t)(b * SS + s0A + wave * 16 + ln) * DIM + h * HD + quad * 8;
    qfA[0] = *(const short8*)qa;
    qfA[1] = *(const short8*)(qa + 32);
    const unsigned short* qb2 =
        Qb + (size_t)(b * SS + s0B + wave * 16 + ln) * DIM + h * HD + quad * 8;
    qfB[0] = *(const short8*)qb2;
    qfB[1] = *(const short8*)(qb2 + 32);
  }

  f32x4 ocA[4], ocB[4]; // PV acc: row q=quad*4+r, col d=dt*16+ln
  float lpA = 0.f, lpB = 0.f;
#pragma unroll
  for (int i = 0; i < 4; i++) {
    ocA[i] = (f32x4){0.f, 0.f, 0.f, 0.f};
    ocB[i] = (f32x4){0.f, 0.f, 0.f, 0.f};
  }

  unsigned short* Pw = Ps + wave * (16 * 64);
  const int swz = (ln & 7) << 3; // read-side XOR (shorts); row&7 == ln&7

  const int srow = tid >> 3, sc8 = (tid & 7) * 8; // 32 rows per shot
  const int ssc = sc8 ^ ((srow & 7) << 3);        // write-side XOR (shorts)

  const unsigned short* kptr =
      KVb + (size_t)(b * SS + srow) * (2 * DIM) + h * HD + sc8;
  const unsigned short* vptr = VTb + (size_t)(b * DIM + h * HD + srow) * SS + sc8;
  const size_t kstep = (size_t)64 * 2 * DIM;
  const size_t krow32 = (size_t)32 * 2 * DIM;
  const size_t vrow32 = (size_t)32 * SS;

  short8 kreg0 = *(const short8*)kptr;
  short8 kreg1 = *(const short8*)(kptr + krow32);
  short8 vreg0 = *(const short8*)vptr;
  short8 vreg1 = *(const short8*)(vptr + vrow32);

  for (int kt = 0; kt <= ktmaxB; ++kt) {
    __syncthreads(); // prior-iter LDS readers done
    *(short8*)(Ks + srow * 64 + ssc) = kreg0;
    *(short8*)(Ks + (srow + 32) * 64 + ssc) = kreg1;
    *(short8*)(Vts + srow * 64 + ssc) = vreg0;
    *(short8*)(Vts + (srow + 32) * 64 + ssc) = vreg1;
    __syncthreads();
    if (kt < ktmaxB) { // prefetch next K/V tile (overlaps compute)
      kptr += kstep; vptr += 64;
      kreg0 = *(const short8*)kptr;
      kreg1 = *(const short8*)(kptr + krow32);
      vreg0 = *(const short8*)vptr;
      vreg1 = *(const short8*)(vptr + vrow32);
    }

    const int k0g = kt * 64;

    auto stream = [&](const short8* qf, f32x4* oc, float& lp, const int qminw,
                      const int qmaxw) {
      if (k0g > qmaxw) return; // whole tile masked for this wave (wave-uniform)
      const bool needmask = (k0g + 63 > qminw);

      f32x4 sacc[4]; // S^T: nt -> keys k0g+nt*16+quad*4+r, col q=ln
#pragma unroll
      for (int nt = 0; nt < 4; nt++) sacc[nt] = (f32x4){0.f, 0.f, 0.f, 0.f};
      __builtin_amdgcn_s_setprio(1);
#pragma unroll
      for (int kc = 0; kc < 2; kc++) {
        const int rc = (kc * 32 + quad * 8) ^ swz;
#pragma unroll
        for (int nt = 0; nt < 4; nt++) {
          if (k0g + nt * 16 > qmaxw) continue; // strip fully masked
          short8 kfrag = *(const short8*)(Ks + (nt * 16 + ln) * 64 + rc);
          sacc[nt] =
              __builtin_amdgcn_mfma_f32_16x16x32_bf16(kfrag, qf[kc], sacc[nt], 0, 0, 0);
        }
      }
      __builtin_amdgcn_s_setprio(0);

      // Fixed-max softmax (scale pre-baked into Q): interior path has no
      // per-element masking VALU at all.
      const int qg = qminw + ln; // this thread's q column (global)
      float lt = 0.f;
      if (!needmask) {
#pragma unroll
        for (int nt = 0; nt < 4; nt++) {
          float p0 = __builtin_exp2f(sacc[nt][0]);
          float p1 = __builtin_exp2f(sacc[nt][1]);
          float p2 = __builtin_exp2f(sacc[nt][2]);
          float p3 = __builtin_exp2f(sacc[nt][3]);
          uint2 pw;
          pw.x = pack_bf16_pair(p0, p1);
          pw.y = pack_bf16_pair(p2, p3);
          *(uint2*)(Pw + ln * 64 + ((nt * 16 + quad * 4) ^ swz)) = pw;
          lt += (p0 + p1) + (p2 + p3);
        }
      } else {
#pragma unroll
        for (int nt = 0; nt < 4; nt++) {
          const int base = k0g + nt * 16 + quad * 4;
          float pe[4];
#pragma unroll
          for (int r = 0; r < 4; r++) {
            float p = __builtin_exp2f(sacc[nt][r]);
            if (base + r > qg) p = 0.f;
            pe[r] = p;
          }
          uint2 pw;
          pw.x = pack_bf16_pair(pe[0], pe[1]);
          pw.y = pack_bf16_pair(pe[2], pe[3]);
          *(uint2*)(Pw + ln * 64 + ((nt * 16 + quad * 4) ^ swz)) = pw;
          lt += (pe[0] + pe[1]) + (pe[2] + pe[3]);
        }
      }
      lp += lt;

      __builtin_amdgcn_s_setprio(1);
#pragma unroll
      for (int kc = 0; kc < 2; kc++) {
        if (k0g + kc * 32 > qmaxw) continue; // P chunk all zero
        const int rc = (kc * 32 + quad * 8) ^ swz;
        short8 pfrag = *(const short8*)(Pw + ln * 64 + rc);
#pragma unroll
        for (int dt = 0; dt < 4; dt++) {
          short8 vfrag = *(const short8*)(Vts + (dt * 16 + ln) * 64 + rc);
          oc[dt] =
              __builtin_amdgcn_mfma_f32_16x16x32_bf16(pfrag, vfrag, oc[dt], 0, 0, 0);
        }
      }
      __builtin_amdgcn_s_setprio(0);
    };

    stream(qfA, ocA, lpA, qminA, qmaxA);
    stream(qfB, ocB, lpB, qminB, qmaxB);
  }

  // Denominators: reduce across the 4 quads, broadcast to owned rows.
  lpA += __shfl_xor(lpA, 16, 64);
  lpA += __shfl_xor(lpA, 32, 64);
  lpB += __shfl_xor(lpB, 16, 64);
  lpB += __shfl_xor(lpB, 32, 64);
  float liA[4], liB[4];
#pragma unroll
  for (int r = 0; r < 4; r++) {
    liA[r] = 1.f / __shfl(lpA, quad * 4 + r, 64);
    liB[r] = 1.f / __shfl(lpB, quad * 4 + r, 64);
  }

  // Epilogue: normalize, stage each 64x64 tile through smem, 16B stores.
  __syncthreads();
#pragma unroll
  for (int r = 0; r < 4; r++) {
#pragma unroll
    for (int dt = 0; dt < 4; dt++)
      smem[(wave * 16 + quad * 4 + r) * 72 + dt * 16 + ln] = f2b(ocA[dt][r] * liA[r]);
  }
  __syncthreads();
#pragma unroll
  for (int t = 0; t < 2; ++t) {
    int idx = tid + t * 256;
    int row = idx >> 3, c = idx & 7;
    short8 v = *(const short8*)(smem + row * 72 + c * 8);
    *(short8*)(ctxB + (size_t)(b * SS + s0A + row) * DIM + h * HD + c * 8) = v;
  }
  __syncthreads();
#pragma unroll
  for (int r = 0; r < 4; r++) {
#pragma unroll
    for (int dt = 0; dt < 4; dt++)
      smem[(wave * 16 + quad * 4 + r) * 72 + dt * 16 + ln] = f2b(ocB[dt][r] * liB[r]);
  }
  __syncthreads();
#pragma unroll
  for (int t = 0; t < 2; ++t) {
    int idx = tid + t * 256;
    int row = idx >> 3, c = idx & 7;
    short8 v = *(const short8*)(smem + row * 72 + c * 8);
    *(short8*)(ctxB + (size_t)(b * SS + s0B + row) * DIM + h * HD + c * 8) = v;
  }
}

extern "C" void kernel_launch(void* const* d_in, const int* in_sizes, int n_in,
                              void* d_out, int out_size, void* d_ws, size_t ws_size,
                              hipStream_t stream) {
  const float* x     = (const float*)d_in[0];
  const float* w_kvc = (const float*)d_in[2];
  const float* b_kvc = (const float*)d_in[3];
  const float* w_kvu = (const float*)d_in[4];
  const float* b_kvu = (const float*)d_in[5];
  const float* w_qc  = (const float*)d_in[6];
  const float* b_qc  = (const float*)d_in[7];
  const float* w_qu  = (const float*)d_in[8];
  const float* b_qu  = (const float*)d_in[9];
  const float* w_o   = (const float*)d_in[10];
  const float* b_o   = (const float*)d_in[11];
  float* out = (float*)d_out;

  unsigned short* xb     = (unsigned short*)d_ws;          // [BS][DIM]; reused as VT
  unsigned short* wcatT  = xb + (size_t)BS * DIM;          // [NCAT][DIM]
  unsigned short* wkvuT  = wcatT + (size_t)NCAT * DIM;     // [2*DIM][LAT]
  unsigned short* wquT   = wkvuT + (size_t)LAT * 2 * DIM;  // [DIM][QR]
  unsigned short* woT    = wquT + (size_t)QR * DIM;        // [DIM][DIM]
  unsigned short* kvqlat = woT + (size_t)DIM * DIM;        // [BS][NCAT] (kv | q)
  unsigned short* kvup   = kvqlat + (size_t)BS * NCAT;     // [BS][2*DIM] (K | dead V)
  unsigned short* Qbuf   = kvup + (size_t)BS * 2 * DIM;    // [BS][DIM]
  unsigned short* ctx    = Qbuf + (size_t)BS * DIM;        // [BS][DIM]
  float* bias_cat        = (float*)(ctx + (size_t)BS * DIM); // [NCAT]

  cvt_x<<<(BS * DIM / 4 + 255) / 256, 256, 0, stream>>>(x, xb, BS * DIM / 4);
  prep_weights<<<481, 256, 0, stream>>>(w_kvc, w_qc, w_kvu, w_qu, w_o, b_kvc, b_qc,
                                        wcatT, wkvuT, wquT, woT, bias_cat);

  // fused stage-1: [kvlat | qlat] = x @ [w_kvc | w_qc]   (8192x384x1024)
  gemm_lds<<<dim3(BS / 128 * (NCAT / 128)), 256, 0, stream>>>(
      xb, wcatT, bias_cat, nullptr, kvqlat, nullptr, NCAT, DIM, DIM, NCAT, 1.0f,
      BS / 128 * (NCAT / 128));
  unsigned short* VT = xb; // xb dead after stage-1
  // stage-2: kvup = kvlat @ w_kvu (8192x2048x128); V-half written transposed
  // straight to VT (fused transpose_v)
  gemm_lds<<<dim3(BS / 128 * (2 * DIM / 128)), 256, 0, stream>>>(
      kvqlat, wkvuT, b_kvu, nullptr, kvup, VT, 2 * DIM, LAT, NCAT, 2 * DIM, 1.0f,
      BS / 128 * (2 * DIM / 128));
  // Q path (8192x1024x256): softmax scale baked into Q here
  gemm_lds<<<dim3(BS / 128 * (DIM / 128)), 256, 0, stream>>>(
      kvqlat + LAT, wquT, b_qu, nullptr, Qbuf, nullptr, DIM, QR, NCAT, DIM, SCALE_LOG2E,
      BS / 128 * (DIM / 128));
  attn_mfma<<<dim3(32 * NH * BB / 2), 256, 0, stream>>>(Qbuf, kvup, VT, ctx);
  // O-proj (8192x1024x1024)
  gemm_lds<<<dim3(BS / 128 * (DIM / 128)), 256, 0, stream>>>(
      ctx, woT, b_o, out, nullptr, nullptr, DIM, DIM, DIM, DIM, 1.0f,
      BS / 128 * (DIM / 128));
}

// Round 9
// 250.247 us; speedup vs baseline: 1.0237x; 1.0237x over previous
//
#include <hip/hip_runtime.h>

typedef __attribute__((ext_vector_type(8))) short short8;
typedef __attribute__((ext_vector_type(4))) float f32x4;

#define DIM 1024
#define NH 16
#define HD 64
#define LAT 128
#define QR 256
#define NCAT (LAT + QR) /* 384 */
#define BB 4
#define SS 2048
#define BS (BB * SS) /* 8192 */

// exp(s*0.125) == exp2(s * 0.125*log2(e)); baked into Q at the GEMM epilogue.
#define SCALE_LOG2E 0.18033688011112042f

__device__ __forceinline__ unsigned short f2b(float f) {
  unsigned int u = __builtin_bit_cast(unsigned int, f);
  u += 0x7FFFu + ((u >> 16) & 1u); // RNE
  return (unsigned short)(u >> 16);
}
__device__ __forceinline__ float b2f(unsigned short h) {
  unsigned int u = ((unsigned int)h) << 16;
  return __builtin_bit_cast(float, u);
}
// pack hi16(f0)|hi16(f1)<<16 with round-half-up (safe: inputs >= 0, no NaN)
__device__ __forceinline__ unsigned int pack_bf16_pair(float f0, float f1) {
  unsigned int u0 = __builtin_bit_cast(unsigned int, f0) + 0x8000u;
  unsigned int u1 = __builtin_bit_cast(unsigned int, f1) + 0x8000u;
  return __builtin_amdgcn_perm(u1, u0, 0x07060302u);
}
// async global->LDS, 16B per lane. LDS dest is wave-uniform base + lane*16.
__device__ __forceinline__ void gll16(const unsigned short* g, unsigned short* l) {
  __builtin_amdgcn_global_load_lds(
      (const __attribute__((address_space(1))) unsigned int*)g,
      (__attribute__((address_space(3))) unsigned int*)l, 16, 0, 0);
}

// Fused: x f32->bf16 convert (blocks 0..8191) + all 5 weight transposes +
// bias concat (blocks 8192..8672). One launch.
__global__ __launch_bounds__(256) void cvt_prep(
    const float* __restrict__ x, unsigned short* __restrict__ xb,
    const float* __restrict__ w_kvc, const float* __restrict__ w_qc,
    const float* __restrict__ w_kvu, const float* __restrict__ w_qu,
    const float* __restrict__ w_o, const float* __restrict__ b_kvc,
    const float* __restrict__ b_qc, unsigned short* __restrict__ wcatT,
    unsigned short* __restrict__ wkvuT, unsigned short* __restrict__ wquT,
    unsigned short* __restrict__ woT, float* __restrict__ bias_cat) {
  __shared__ unsigned short T[64 * 72];
  const int tid = threadIdx.x;
  if (blockIdx.x < 8192) { // cvt_x: 8192*256*4 = BS*DIM elements
    int i = blockIdx.x * 256 + tid;
    f32x4 v = ((const f32x4*)x)[i];
    ushort4 o;
    o.x = f2b(v[0]); o.y = f2b(v[1]); o.z = f2b(v[2]); o.w = f2b(v[3]);
    ((ushort4*)xb)[i] = o;
    return;
  }
  const int id = blockIdx.x - 8192;
  if (id >= 480) { // bias concat (384 floats)
    if (tid < LAT) bias_cat[tid] = b_kvc[tid];
    else bias_cat[tid] = b_qc[tid - LAT];
    if (tid < 128) bias_cat[tid + 256] = b_qc[tid + 128];
    return;
  }
  const float* in; unsigned short* out; int K, N, tile;
  if (id < 32)       { in = w_kvc; out = wcatT;                       K = DIM; N = LAT;     tile = id; }
  else if (id < 96)  { in = w_qc;  out = wcatT + (size_t)LAT * DIM;   K = DIM; N = QR;      tile = id - 32; }
  else if (id < 160) { in = w_kvu; out = wkvuT;                       K = LAT; N = 2 * DIM; tile = id - 96; }
  else if (id < 224) { in = w_qu;  out = wquT;                        K = QR;  N = DIM;     tile = id - 160; }
  else               { in = w_o;   out = woT;                         K = DIM; N = DIM;     tile = id - 224; }
  const int ktiles = K >> 6;
  const int k0 = (tile % ktiles) * 64, n0 = (tile / ktiles) * 64;
  {
    const int r = tid >> 2, cq = (tid & 3) * 16;
#pragma unroll
    for (int j = 0; j < 4; ++j) {
      f32x4 v = *(const f32x4*)(in + (size_t)(k0 + r) * N + n0 + cq + j * 4);
      ushort4 o;
      o.x = f2b(v[0]); o.y = f2b(v[1]); o.z = f2b(v[2]); o.w = f2b(v[3]);
      *(ushort4*)(T + r * 72 + cq + j * 4) = o;
    }
  }
  __syncthreads();
#pragma unroll
  for (int s = 0; s < 2; ++s) {
    int idx = tid + s * 256;
    int nr = idx >> 3, kg = (idx & 7) * 8;
    short8 o;
#pragma unroll
    for (int i = 0; i < 8; i++) o[i] = T[(kg + i) * 72 + nr];
    *(short8*)(out + (size_t)(n0 + nr) * K + k0 + kg) = o;
  }
}

// GEMM body, BM=64 x BN=128 tiles (grid-occupancy geometry for small-N
// shapes: doubles block count vs BM=128 -> 4 blocks/CU on O-proj/Q/s2).
// 2-phase double-buffered BK=32 (R7-proven), source-side conflict swizzle
// (R8-proven, rule #21: global col pre-swizzled cg^=row&3, LDS linear,
// read XOR'd). 4 waves, 32x64/wave, 3 gll16/wave/step. LDS 24 KB (+VT
// union 34 KB). vtOut: blocks with n0 >= DIM write tile transposed.
__device__ __forceinline__ void gemm_body(
    const unsigned short* __restrict__ A, const unsigned short* __restrict__ WT,
    const float* __restrict__ bias, float* __restrict__ outF,
    unsigned short* __restrict__ outB, unsigned short* __restrict__ vtOut,
    int N, int K, int lda, int ldout, float scale, int nblk, int bid,
    unsigned short* gsm) {
  const int tid = threadIdx.x;
  const int wave = tid >> 6, lane = tid & 63;
  const int ln = lane & 15, quad = lane >> 4;
  const int chunk = nblk >> 3;
  const int sw = (bid & 7) * chunk + (bid >> 3); // XCD-chunked swizzle (T1)
  const int nwx = N >> 7;
  const int bx = sw % nwx, by = sw / nwx;
  const int m0 = by * 64, n0 = bx * 128;
  const int wm = (wave >> 1) * 32, wn = (wave & 1) * 64;

  // staging: A rows wave*16..+15 (1 gll), B rows wave*32..+31 (2 glls).
  // global source col pre-swizzled cg^(row&3); LDS dest linear.
  const int sr = lane >> 2;
  const int scg = (lane & 3) ^ (sr & 3);
  const unsigned short* Ag = A + (size_t)(m0 + wave * 16 + sr) * lda + scg * 8;
  const unsigned short* Bg = WT + (size_t)(n0 + wave * 32 + sr) * K + scg * 8;

  f32x4 acc[2][4];
#pragma unroll
  for (int i = 0; i < 2; i++)
#pragma unroll
    for (int j = 0; j < 4; j++) acc[i][j] = (f32x4){0.f, 0.f, 0.f, 0.f};

#define STAGE(buf, kk)                                                        \
  {                                                                           \
    unsigned short* Al = gsm + (buf) * 2048 + wave * 512;                     \
    unsigned short* Bl = gsm + 4096 + (buf) * 4096 + wave * 1024;             \
    gll16(Ag + (kk), Al);                                                     \
    gll16(Bg + (kk), Bl);                                                     \
    gll16(Bg + (size_t)16 * K + (kk), Bl + 512);                              \
  }

  const int T = K >> 5;
  STAGE(0, 0);
  __syncthreads(); // drains vmcnt(0): tile 0 visible
  int cur = 0;
  const int rc = (quad ^ (ln & 3)) * 8; // swizzled fragment col (shorts)
  for (int t = 0; t < T; ++t) {
    if (t + 1 < T) STAGE(cur ^ 1, (t + 1) * 32); // async; drains at loop-end
    const unsigned short* Ab = gsm + cur * 2048;
    const unsigned short* Bb = gsm + 4096 + cur * 4096;
    short8 af[2], bf[4];
#pragma unroll
    for (int i = 0; i < 2; i++)
      af[i] = *(const short8*)(Ab + (wm + i * 16 + ln) * 32 + rc);
#pragma unroll
    for (int i = 0; i < 4; i++)
      bf[i] = *(const short8*)(Bb + (wn + i * 16 + ln) * 32 + rc);
#pragma unroll
    for (int mi = 0; mi < 2; mi++)
#pragma unroll
      for (int ni = 0; ni < 4; ni++)
        acc[mi][ni] =
            __builtin_amdgcn_mfma_f32_16x16x32_bf16(af[mi], bf[ni], acc[mi][ni], 0, 0, 0);
    __syncthreads(); // readers done + next stage complete (vmcnt drain here)
    cur ^= 1;
  }
#undef STAGE

  if (vtOut && n0 >= DIM) {
    // Fused V-transpose: stage 64s x 128d tile transposed, write VT rows.
#pragma unroll
    for (int mi = 0; mi < 2; mi++) {
      const int s = wm + mi * 16 + quad * 4;
#pragma unroll
      for (int ni = 0; ni < 4; ni++) {
        const int d = wn + ni * 16 + ln;
        const float bv = bias[n0 + d];
#pragma unroll
        for (int r = 0; r < 4; r++)
          gsm[d * 72 + s + r] = f2b(acc[mi][ni][r] + bv);
      }
    }
    __syncthreads();
    const int d0 = n0 - DIM, bb = m0 >> 11, s0l = m0 & (SS - 1);
#pragma unroll
    for (int t = 0; t < 4; ++t) {
      int idx = tid + t * 256;
      int dr = idx >> 3, cs = (idx & 7) * 8;
      short8 v = *(const short8*)(gsm + dr * 72 + cs);
      *(short8*)(vtOut + (size_t)(bb * DIM + d0 + dr) * SS + s0l + cs) = v;
    }
    return;
  }

#pragma unroll
  for (int mi = 0; mi < 2; mi++) {
    const int row = m0 + wm + mi * 16 + quad * 4;
#pragma unroll
    for (int ni = 0; ni < 4; ni++) {
      const int col = n0 + wn + ni * 16 + ln;
      const float bv = bias[col];
#pragma unroll
      for (int r = 0; r < 4; r++) {
        float v = (acc[mi][ni][r] + bv) * scale;
        size_t o = (size_t)(row + r) * ldout + col;
        if (outF) outF[o] = v;
        if (outB) outB[o] = f2b(v);
      }
    }
  }
}

__global__ __launch_bounds__(256, 4) void gemm_lds(const unsigned short* __restrict__ A,
                                                   const unsigned short* __restrict__ WT,
                                                   const float* __restrict__ bias,
                                                   float* __restrict__ outF,
                                                   unsigned short* __restrict__ outB,
                                                   unsigned short* __restrict__ vtOut,
                                                   int N, int K, int lda, int ldout,
                                                   float scale, int nblk) {
  __shared__ unsigned short gsm[17408];
  gemm_body(A, WT, bias, outF, outB, vtOut, N, K, lda, ldout, scale, nblk,
            blockIdx.x, gsm);
}

// Fused stage-2 + Q-path (both read kvqlat, mutually independent): blocks
// 0..2047 = stage-2 (N=2048, K=128, fused V-transpose), 2048..3071 = Q-path
// (N=1024, K=256, softmax scale baked in). Tails overlap; one launch gap gone.
__global__ __launch_bounds__(256, 4) void gemm_s2q(
    const unsigned short* __restrict__ kvqlat, const unsigned short* __restrict__ wkvuT,
    const unsigned short* __restrict__ wquT, const float* __restrict__ b_kvu,
    const float* __restrict__ b_qu, unsigned short* __restrict__ kvup,
    unsigned short* __restrict__ VT, unsigned short* __restrict__ Qbuf) {
  __shared__ unsigned short gsm[17408];
  if (blockIdx.x < 2048)
    gemm_body(kvqlat, wkvuT, b_kvu, nullptr, kvup, VT, 2 * DIM, LAT, NCAT,
              2 * DIM, 1.0f, 2048, blockIdx.x, gsm);
  else
    gemm_body(kvqlat + LAT, wquT, b_qu, nullptr, Qbuf, nullptr, DIM, QR, NCAT,
              DIM, SCALE_LOG2E, 1024, blockIdx.x - 2048, gsm);
}

// MFMA flash attention, causal, fixed-max softmax, S^T orientation.
// FROZEN (measured 80.5 us): sequential streams, antidiagonal pairing
// (tA=pair, tB=31-pair; uniform 33 units), 1024 blocks = 4/CU,
// XCD-affinity decode (K/V L2-resident, FETCH ~25 MB), XOR swizzle
// (conflicts 2.2e6).
__global__ __launch_bounds__(256, 4) void attn_mfma(const unsigned short* __restrict__ Qb,
                                                    const unsigned short* __restrict__ KVb,
                                                    const unsigned short* __restrict__ VTb,
                                                    unsigned short* __restrict__ ctxB) {
  __shared__ unsigned short smem[12288]; // 24576 B
  unsigned short* Ks = smem;             // [64 key][64 d] swz
  unsigned short* Vts = smem + 4096;     // [64 d][64 key] swz
  unsigned short* Ps = smem + 8192;      // 4 waves x [16 q][64 key] swz
  const int tid = threadIdx.x;
  const int wave = tid >> 6, lane = tid & 63;
  const int ln = lane & 15, quad = lane >> 4;
  // XCD-affinity decode (all 16 pair-blocks of one (b,h) on one XCD)
  const int hw = blockIdx.x;              // 0..1023
  const int xcd = hw & 7, slot = hw >> 3; // slot 0..127
  const int grp = xcd * 8 + (slot >> 4);  // 0..63 = (b,h) group
  const int pair = slot & 15;             // 0..15
  const int h = grp & 15, b = grp >> 4;
  const int tA = pair, tB = 31 - pair;    // 64-row q-tile indices, tB > tA
  const int s0A = tA * 64, s0B = tB * 64;
  const int ktmaxB = tB;                  // inclusive
  const int qminA = s0A + wave * 16, qmaxA = qminA + 15;
  const int qminB = s0B + wave * 16, qmaxB = qminB + 15;

  short8 qfA[2], qfB[2]; // B-operand: rows = q
  {
    const unsigned short* qa =
        Qb + (size_t)(b * SS + s0A + wave * 16 + ln) * DIM + h * HD + quad * 8;
    qfA[0] = *(const short8*)qa;
    qfA[1] = *(const short8*)(qa + 32);
    const unsigned short* qb2 =
        Qb + (size_t)(b * SS + s0B + wave * 16 + ln) * DIM + h * HD + quad * 8;
    qfB[0] = *(const short8*)qb2;
    qfB[1] = *(const short8*)(qb2 + 32);
  }

  f32x4 ocA[4], ocB[4]; // PV acc: row q=quad*4+r, col d=dt*16+ln
  float lpA = 0.f, lpB = 0.f;
#pragma unroll
  for (int i = 0; i < 4; i++) {
    ocA[i] = (f32x4){0.f, 0.f, 0.f, 0.f};
    ocB[i] = (f32x4){0.f, 0.f, 0.f, 0.f};
  }

  unsigned short* Pw = Ps + wave * (16 * 64);
  const int swz = (ln & 7) << 3; // read-side XOR (shorts); row&7 == ln&7

  const int srow = tid >> 3, sc8 = (tid & 7) * 8; // 32 rows per shot
  const int ssc = sc8 ^ ((srow & 7) << 3);        // write-side XOR (shorts)

  const unsigned short* kptr =
      KVb + (size_t)(b * SS + srow) * (2 * DIM) + h * HD + sc8;
  const unsigned short* vptr = VTb + (size_t)(b * DIM + h * HD + srow) * SS + sc8;
  const size_t kstep = (size_t)64 * 2 * DIM;
  const size_t krow32 = (size_t)32 * 2 * DIM;
  const size_t vrow32 = (size_t)32 * SS;

  short8 kreg0 = *(const short8*)kptr;
  short8 kreg1 = *(const short8*)(kptr + krow32);
  short8 vreg0 = *(const short8*)vptr;
  short8 vreg1 = *(const short8*)(vptr + vrow32);

  for (int kt = 0; kt <= ktmaxB; ++kt) {
    __syncthreads(); // prior-iter LDS readers done
    *(short8*)(Ks + srow * 64 + ssc) = kreg0;
    *(short8*)(Ks + (srow + 32) * 64 + ssc) = kreg1;
    *(short8*)(Vts + srow * 64 + ssc) = vreg0;
    *(short8*)(Vts + (srow + 32) * 64 + ssc) = vreg1;
    __syncthreads();
    if (kt < ktmaxB) { // prefetch next K/V tile (overlaps compute)
      kptr += kstep; vptr += 64;
      kreg0 = *(const short8*)kptr;
      kreg1 = *(const short8*)(kptr + krow32);
      vreg0 = *(const short8*)vptr;
      vreg1 = *(const short8*)(vptr + vrow32);
    }

    const int k0g = kt * 64;

    auto stream = [&](const short8* qf, f32x4* oc, float& lp, const int qminw,
                      const int qmaxw) {
      if (k0g > qmaxw) return; // whole tile masked for this wave (wave-uniform)
      const bool needmask = (k0g + 63 > qminw);

      f32x4 sacc[4]; // S^T: nt -> keys k0g+nt*16+quad*4+r, col q=ln
#pragma unroll
      for (int nt = 0; nt < 4; nt++) sacc[nt] = (f32x4){0.f, 0.f, 0.f, 0.f};
      __builtin_amdgcn_s_setprio(1);
#pragma unroll
      for (int kc = 0; kc < 2; kc++) {
        const int rc = (kc * 32 + quad * 8) ^ swz;
#pragma unroll
        for (int nt = 0; nt < 4; nt++) {
          if (k0g + nt * 16 > qmaxw) continue; // strip fully masked
          short8 kfrag = *(const short8*)(Ks + (nt * 16 + ln) * 64 + rc);
          sacc[nt] =
              __builtin_amdgcn_mfma_f32_16x16x32_bf16(kfrag, qf[kc], sacc[nt], 0, 0, 0);
        }
      }
      __builtin_amdgcn_s_setprio(0);

      // Fixed-max softmax (scale pre-baked into Q): interior path has no
      // per-element masking VALU at all.
      const int qg = qminw + ln; // this thread's q column (global)
      float lt = 0.f;
      if (!needmask) {
#pragma unroll
        for (int nt = 0; nt < 4; nt++) {
          float p0 = __builtin_exp2f(sacc[nt][0]);
          float p1 = __builtin_exp2f(sacc[nt][1]);
          float p2 = __builtin_exp2f(sacc[nt][2]);
          float p3 = __builtin_exp2f(sacc[nt][3]);
          uint2 pw;
          pw.x = pack_bf16_pair(p0, p1);
          pw.y = pack_bf16_pair(p2, p3);
          *(uint2*)(Pw + ln * 64 + ((nt * 16 + quad * 4) ^ swz)) = pw;
          lt += (p0 + p1) + (p2 + p3);
        }
      } else {
#pragma unroll
        for (int nt = 0; nt < 4; nt++) {
          const int base = k0g + nt * 16 + quad * 4;
          float pe[4];
#pragma unroll
          for (int r = 0; r < 4; r++) {
            float p = __builtin_exp2f(sacc[nt][r]);
            if (base + r > qg) p = 0.f;
            pe[r] = p;
          }
          uint2 pw;
          pw.x = pack_bf16_pair(pe[0], pe[1]);
          pw.y = pack_bf16_pair(pe[2], pe[3]);
          *(uint2*)(Pw + ln * 64 + ((nt * 16 + quad * 4) ^ swz)) = pw;
          lt += (pe[0] + pe[1]) + (pe[2] + pe[3]);
        }
      }
      lp += lt;

      __builtin_amdgcn_s_setprio(1);
#pragma unroll
      for (int kc = 0; kc < 2; kc++) {
        if (k0g + kc * 32 > qmaxw) continue; // P chunk all zero
        const int rc = (kc * 32 + quad * 8) ^ swz;
        short8 pfrag = *(const short8*)(Pw + ln * 64 + rc);
#pragma unroll
        for (int dt = 0; dt < 4; dt++) {
          short8 vfrag = *(const short8*)(Vts + (dt * 16 + ln) * 64 + rc);
          oc[dt] =
              __builtin_amdgcn_mfma_f32_16x16x32_bf16(pfrag, vfrag, oc[dt], 0, 0, 0);
        }
      }
      __builtin_amdgcn_s_setprio(0);
    };

    stream(qfA, ocA, lpA, qminA, qmaxA);
    stream(qfB, ocB, lpB, qminB, qmaxB);
  }

  // Denominators: reduce across the 4 quads, broadcast to owned rows.
  lpA += __shfl_xor(lpA, 16, 64);
  lpA += __shfl_xor(lpA, 32, 64);
  lpB += __shfl_xor(lpB, 16, 64);
  lpB += __shfl_xor(lpB, 32, 64);
  float liA[4], liB[4];
#pragma unroll
  for (int r = 0; r < 4; r++) {
    liA[r] = 1.f / __shfl(lpA, quad * 4 + r, 64);
    liB[r] = 1.f / __shfl(lpB, quad * 4 + r, 64);
  }

  // Epilogue: normalize, stage each 64x64 tile through smem, 16B stores.
  __syncthreads();
#pragma unroll
  for (int r = 0; r < 4; r++) {
#pragma unroll
    for (int dt = 0; dt < 4; dt++)
      smem[(wave * 16 + quad * 4 + r) * 72 + dt * 16 + ln] = f2b(ocA[dt][r] * liA[r]);
  }
  __syncthreads();
#pragma unroll
  for (int t = 0; t < 2; ++t) {
    int idx = tid + t * 256;
    int row = idx >> 3, c = idx & 7;
    short8 v = *(const short8*)(smem + row * 72 + c * 8);
    *(short8*)(ctxB + (size_t)(b * SS + s0A + row) * DIM + h * HD + c * 8) = v;
  }
  __syncthreads();
#pragma unroll
  for (int r = 0; r < 4; r++) {
#pragma unroll
    for (int dt = 0; dt < 4; dt++)
      smem[(wave * 16 + quad * 4 + r) * 72 + dt * 16 + ln] = f2b(ocB[dt][r] * liB[r]);
  }
  __syncthreads();
#pragma unroll
  for (int t = 0; t < 2; ++t) {
    int idx = tid + t * 256;
    int row = idx >> 3, c = idx & 7;
    short8 v = *(const short8*)(smem + row * 72 + c * 8);
    *(short8*)(ctxB + (size_t)(b * SS + s0B + row) * DIM + h * HD + c * 8) = v;
  }
}

extern "C" void kernel_launch(void* const* d_in, const int* in_sizes, int n_in,
                              void* d_out, int out_size, void* d_ws, size_t ws_size,
                              hipStream_t stream) {
  const float* x     = (const float*)d_in[0];
  const float* w_kvc = (const float*)d_in[2];
  const float* b_kvc = (const float*)d_in[3];
  const float* w_kvu = (const float*)d_in[4];
  const float* b_kvu = (const float*)d_in[5];
  const float* w_qc  = (const float*)d_in[6];
  const float* b_qc  = (const float*)d_in[7];
  const float* w_qu  = (const float*)d_in[8];
  const float* b_qu  = (const float*)d_in[9];
  const float* w_o   = (const float*)d_in[10];
  const float* b_o   = (const float*)d_in[11];
  float* out = (float*)d_out;

  unsigned short* xb     = (unsigned short*)d_ws;          // [BS][DIM]; reused as VT
  unsigned short* wcatT  = xb + (size_t)BS * DIM;          // [NCAT][DIM]
  unsigned short* wkvuT  = wcatT + (size_t)NCAT * DIM;     // [2*DIM][LAT]
  unsigned short* wquT   = wkvuT + (size_t)LAT * 2 * DIM;  // [DIM][QR]
  unsigned short* woT    = wquT + (size_t)QR * DIM;        // [DIM][DIM]
  unsigned short* kvqlat = woT + (size_t)DIM * DIM;        // [BS][NCAT] (kv | q)
  unsigned short* kvup   = kvqlat + (size_t)BS * NCAT;     // [BS][2*DIM] (K | dead V)
  unsigned short* Qbuf   = kvup + (size_t)BS * 2 * DIM;    // [BS][DIM]
  unsigned short* ctx    = Qbuf + (size_t)BS * DIM;        // [BS][DIM]
  float* bias_cat        = (float*)(ctx + (size_t)BS * DIM); // [NCAT]

  // fused convert + weight prep (one launch)
  cvt_prep<<<8673, 256, 0, stream>>>(x, xb, w_kvc, w_qc, w_kvu, w_qu, w_o,
                                     b_kvc, b_qc, wcatT, wkvuT, wquT, woT,
                                     bias_cat);

  // stage-1: [kvlat | qlat] = x @ [w_kvc | w_qc]   (8192x384x1024), 384 blocks
  gemm_lds<<<384, 256, 0, stream>>>(xb, wcatT, bias_cat, nullptr, kvqlat,
                                    nullptr, NCAT, DIM, DIM, NCAT, 1.0f, 384);
  unsigned short* VT = xb; // xb dead after stage-1
  // fused stage-2 (8192x2048x128, V written transposed to VT) + Q-path
  // (8192x1024x256, softmax scale baked in): 3072 blocks
  gemm_s2q<<<3072, 256, 0, stream>>>(kvqlat, wkvuT, wquT, b_kvu, b_qu, kvup,
                                     VT, Qbuf);
  attn_mfma<<<1024, 256, 0, stream>>>(Qbuf, kvup, VT, ctx);
  // O-proj (8192x1024x1024), 1024 blocks
  gemm_lds<<<1024, 256, 0, stream>>>(ctx, woT, b_o, out, nullptr, nullptr,
                                     DIM, DIM, DIM, DIM, 1.0f, 1024);
}

// Round 10
// 250.186 us; speedup vs baseline: 1.0239x; 1.0002x over previous
//
#include <hip/hip_runtime.h>

typedef __attribute__((ext_vector_type(8))) short short8;
typedef __attribute__((ext_vector_type(4))) float f32x4;

#define DIM 1024
#define NH 16
#define HD 64
#define LAT 128
#define QR 256
#define NCAT (LAT + QR) /* 384 */
#define BB 4
#define SS 2048
#define BS (BB * SS) /* 8192 */

// exp(s*0.125) == exp2(s * 0.125*log2(e)); baked into Q at the GEMM epilogue.
#define SCALE_LOG2E 0.18033688011112042f

__device__ __forceinline__ unsigned short f2b(float f) {
  unsigned int u = __builtin_bit_cast(unsigned int, f);
  u += 0x7FFFu + ((u >> 16) & 1u); // RNE
  return (unsigned short)(u >> 16);
}
__device__ __forceinline__ float b2f(unsigned short h) {
  unsigned int u = ((unsigned int)h) << 16;
  return __builtin_bit_cast(float, u);
}
// pack hi16(f0)|hi16(f1)<<16 with round-half-up (safe: inputs >= 0, no NaN)
__device__ __forceinline__ unsigned int pack_bf16_pair(float f0, float f1) {
  unsigned int u0 = __builtin_bit_cast(unsigned int, f0) + 0x8000u;
  unsigned int u1 = __builtin_bit_cast(unsigned int, f1) + 0x8000u;
  return __builtin_amdgcn_perm(u1, u0, 0x07060302u);
}
// async global->LDS, 16B per lane. LDS dest is wave-uniform base + lane*16.
__device__ __forceinline__ void gll16(const unsigned short* g, unsigned short* l) {
  __builtin_amdgcn_global_load_lds(
      (const __attribute__((address_space(1))) unsigned int*)g,
      (__attribute__((address_space(3))) unsigned int*)l, 16, 0, 0);
}

// Fused: x f32->bf16 convert (blocks 0..8191) + all 5 weight transposes +
// bias concat (blocks 8192..8672). One launch.
__global__ __launch_bounds__(256) void cvt_prep(
    const float* __restrict__ x, unsigned short* __restrict__ xb,
    const float* __restrict__ w_kvc, const float* __restrict__ w_qc,
    const float* __restrict__ w_kvu, const float* __restrict__ w_qu,
    const float* __restrict__ w_o, const float* __restrict__ b_kvc,
    const float* __restrict__ b_qc, unsigned short* __restrict__ wcatT,
    unsigned short* __restrict__ wkvuT, unsigned short* __restrict__ wquT,
    unsigned short* __restrict__ woT, float* __restrict__ bias_cat) {
  __shared__ unsigned short T[64 * 72];
  const int tid = threadIdx.x;
  if (blockIdx.x < 8192) { // cvt_x: 8192*256*4 = BS*DIM elements
    int i = blockIdx.x * 256 + tid;
    f32x4 v = ((const f32x4*)x)[i];
    ushort4 o;
    o.x = f2b(v[0]); o.y = f2b(v[1]); o.z = f2b(v[2]); o.w = f2b(v[3]);
    ((ushort4*)xb)[i] = o;
    return;
  }
  const int id = blockIdx.x - 8192;
  if (id >= 480) { // bias concat (384 floats)
    if (tid < LAT) bias_cat[tid] = b_kvc[tid];
    else bias_cat[tid] = b_qc[tid - LAT];
    if (tid < 128) bias_cat[tid + 256] = b_qc[tid + 128];
    return;
  }
  const float* in; unsigned short* out; int K, N, tile;
  if (id < 32)       { in = w_kvc; out = wcatT;                       K = DIM; N = LAT;     tile = id; }
  else if (id < 96)  { in = w_qc;  out = wcatT + (size_t)LAT * DIM;   K = DIM; N = QR;      tile = id - 32; }
  else if (id < 160) { in = w_kvu; out = wkvuT;                       K = LAT; N = 2 * DIM; tile = id - 96; }
  else if (id < 224) { in = w_qu;  out = wquT;                        K = QR;  N = DIM;     tile = id - 160; }
  else               { in = w_o;   out = woT;                         K = DIM; N = DIM;     tile = id - 224; }
  const int ktiles = K >> 6;
  const int k0 = (tile % ktiles) * 64, n0 = (tile / ktiles) * 64;
  {
    const int r = tid >> 2, cq = (tid & 3) * 16;
#pragma unroll
    for (int j = 0; j < 4; ++j) {
      f32x4 v = *(const f32x4*)(in + (size_t)(k0 + r) * N + n0 + cq + j * 4);
      ushort4 o;
      o.x = f2b(v[0]); o.y = f2b(v[1]); o.z = f2b(v[2]); o.w = f2b(v[3]);
      *(ushort4*)(T + r * 72 + cq + j * 4) = o;
    }
  }
  __syncthreads();
#pragma unroll
  for (int s = 0; s < 2; ++s) {
    int idx = tid + s * 256;
    int nr = idx >> 3, kg = (idx & 7) * 8;
    short8 o;
#pragma unroll
    for (int i = 0; i < 8; i++) o[i] = T[(kg + i) * 72 + nr];
    *(short8*)(out + (size_t)(n0 + nr) * K + k0 + kg) = o;
  }
}

// GEMM body, BM=64 x BN=128 (R9 geometry, 4 blocks/CU) + 3-DEEP RING with
// counted vmcnt (lookahead-2): per step {vmcnt(3) -> lgkmcnt(0) -> barrier
// -> issue STAGE(t+2) -> ds_read + MFMA}. Stage t's 3 gll16 complete before
// the barrier publishes them; buf((t+2)%3)'s prior occupant (stage t-1) was
// fully read before this barrier. Never drains vmcnt to 0 mid-loop (T4).
// Source-side conflict swizzle (rule #21). LDS 36 KB -> 4 blocks/CU kept.
// vtOut: blocks with n0 >= DIM write tile transposed (fused V-transpose).
__device__ __forceinline__ void gemm_body(
    const unsigned short* __restrict__ A, const unsigned short* __restrict__ WT,
    const float* __restrict__ bias, float* __restrict__ outF,
    unsigned short* __restrict__ outB, unsigned short* __restrict__ vtOut,
    int N, int K, int lda, int ldout, float scale, int nblk, int bid,
    unsigned short* gsm) {
  const int tid = threadIdx.x;
  const int wave = tid >> 6, lane = tid & 63;
  const int ln = lane & 15, quad = lane >> 4;
  const int chunk = nblk >> 3;
  const int sw = (bid & 7) * chunk + (bid >> 3); // XCD-chunked swizzle (T1)
  const int nwx = N >> 7;
  const int bx = sw % nwx, by = sw / nwx;
  const int m0 = by * 64, n0 = bx * 128;
  const int wm = (wave >> 1) * 32, wn = (wave & 1) * 64;

  // staging: A rows wave*16..+15 (1 gll), B rows wave*32..+31 (2 glls).
  // global source col pre-swizzled cg^(row&3); LDS dest linear.
  const int sr = lane >> 2;
  const int scg = (lane & 3) ^ (sr & 3);
  const unsigned short* Ag = A + (size_t)(m0 + wave * 16 + sr) * lda + scg * 8;
  const unsigned short* Bg = WT + (size_t)(n0 + wave * 32 + sr) * K + scg * 8;

  f32x4 acc[2][4];
#pragma unroll
  for (int i = 0; i < 2; i++)
#pragma unroll
    for (int j = 0; j < 4; j++) acc[i][j] = (f32x4){0.f, 0.f, 0.f, 0.f};

  // A ring: 3 x 2048 shorts at gsm[0..6144); B ring: 3 x 4096 at gsm[6144..)
#define STAGE(buf, kk)                                                        \
  {                                                                           \
    unsigned short* Al = gsm + (buf) * 2048 + wave * 512;                     \
    unsigned short* Bl = gsm + 6144 + (buf) * 4096 + wave * 1024;             \
    gll16(Ag + (kk), Al);                                                     \
    gll16(Bg + (kk), Bl);                                                     \
    gll16(Bg + (size_t)16 * K + (kk), Bl + 512);                              \
  }

  const int T = K >> 5; // >= 4 at all call sites
  STAGE(0, 0);
  STAGE(1, 32);

  const int rc = (quad ^ (ln & 3)) * 8; // swizzled fragment col (shorts)
  for (int t = 0; t < T; ++t) {
    // stage-t completion: outstanding = stages {t, t+1} (6 loads) except at
    // t==T-1 where only stage t (3 loads) remains.
    if (t + 1 < T) asm volatile("s_waitcnt vmcnt(3)" ::: "memory");
    else           asm volatile("s_waitcnt vmcnt(0)" ::: "memory");
    asm volatile("s_waitcnt lgkmcnt(0)" ::: "memory"); // prior reads consumed
    __builtin_amdgcn_s_barrier();
    if (t + 2 < T) {
      const int nb = (t + 2) % 3;
      STAGE(nb, (t + 2) * 32);
    }
    const unsigned short* Ab = gsm + (t % 3) * 2048;
    const unsigned short* Bb = gsm + 6144 + (t % 3) * 4096;
    short8 af[2], bf[4];
#pragma unroll
    for (int i = 0; i < 2; i++)
      af[i] = *(const short8*)(Ab + (wm + i * 16 + ln) * 32 + rc);
#pragma unroll
    for (int i = 0; i < 4; i++)
      bf[i] = *(const short8*)(Bb + (wn + i * 16 + ln) * 32 + rc);
#pragma unroll
    for (int mi = 0; mi < 2; mi++)
#pragma unroll
      for (int ni = 0; ni < 4; ni++)
        acc[mi][ni] =
            __builtin_amdgcn_mfma_f32_16x16x32_bf16(af[mi], bf[ni], acc[mi][ni], 0, 0, 0);
  }
#undef STAGE

  if (vtOut && n0 >= DIM) {
    // Fused V-transpose: stage 64s x 128d tile transposed, write VT rows.
    __syncthreads(); // all waves done with ring reads before gsm reuse
#pragma unroll
    for (int mi = 0; mi < 2; mi++) {
      const int s = wm + mi * 16 + quad * 4;
#pragma unroll
      for (int ni = 0; ni < 4; ni++) {
        const int d = wn + ni * 16 + ln;
        const float bv = bias[n0 + d];
#pragma unroll
        for (int r = 0; r < 4; r++)
          gsm[d * 72 + s + r] = f2b(acc[mi][ni][r] + bv);
      }
    }
    __syncthreads();
    const int d0 = n0 - DIM, bb = m0 >> 11, s0l = m0 & (SS - 1);
#pragma unroll
    for (int t = 0; t < 4; ++t) {
      int idx = tid + t * 256;
      int dr = idx >> 3, cs = (idx & 7) * 8;
      short8 v = *(const short8*)(gsm + dr * 72 + cs);
      *(short8*)(vtOut + (size_t)(bb * DIM + d0 + dr) * SS + s0l + cs) = v;
    }
    return;
  }

#pragma unroll
  for (int mi = 0; mi < 2; mi++) {
    const int row = m0 + wm + mi * 16 + quad * 4;
#pragma unroll
    for (int ni = 0; ni < 4; ni++) {
      const int col = n0 + wn + ni * 16 + ln;
      const float bv = bias[col];
#pragma unroll
      for (int r = 0; r < 4; r++) {
        float v = (acc[mi][ni][r] + bv) * scale;
        size_t o = (size_t)(row + r) * ldout + col;
        if (outF) outF[o] = v;
        if (outB) outB[o] = f2b(v);
      }
    }
  }
}

__global__ __launch_bounds__(256, 4) void gemm_lds(const unsigned short* __restrict__ A,
                                                   const unsigned short* __restrict__ WT,
                                                   const float* __restrict__ bias,
                                                   float* __restrict__ outF,
                                                   unsigned short* __restrict__ outB,
                                                   unsigned short* __restrict__ vtOut,
                                                   int N, int K, int lda, int ldout,
                                                   float scale, int nblk) {
  __shared__ unsigned short gsm[18432]; // 36864 B: ring 3x(A 4KB + B 8KB)
  gemm_body(A, WT, bias, outF, outB, vtOut, N, K, lda, ldout, scale, nblk,
            blockIdx.x, gsm);
}

// Fused stage-2 + Q-path (both read kvqlat, mutually independent): blocks
// 0..2047 = stage-2 (N=2048, K=128, fused V-transpose), 2048..3071 = Q-path
// (N=1024, K=256, softmax scale baked in). Tails overlap; one launch gap gone.
__global__ __launch_bounds__(256, 4) void gemm_s2q(
    const unsigned short* __restrict__ kvqlat, const unsigned short* __restrict__ wkvuT,
    const unsigned short* __restrict__ wquT, const float* __restrict__ b_kvu,
    const float* __restrict__ b_qu, unsigned short* __restrict__ kvup,
    unsigned short* __restrict__ VT, unsigned short* __restrict__ Qbuf) {
  __shared__ unsigned short gsm[18432];
  if (blockIdx.x < 2048)
    gemm_body(kvqlat, wkvuT, b_kvu, nullptr, kvup, VT, 2 * DIM, LAT, NCAT,
              2 * DIM, 1.0f, 2048, blockIdx.x, gsm);
  else
    gemm_body(kvqlat + LAT, wquT, b_qu, nullptr, Qbuf, nullptr, DIM, QR, NCAT,
              DIM, SCALE_LOG2E, 1024, blockIdx.x - 2048, gsm);
}

// MFMA flash attention, causal, fixed-max softmax, S^T orientation.
// FROZEN (measured 80.5 us): sequential streams, antidiagonal pairing
// (tA=pair, tB=31-pair; uniform 33 units), 1024 blocks = 4/CU,
// XCD-affinity decode (K/V L2-resident, FETCH ~25 MB), XOR swizzle
// (conflicts 2.2e6).
__global__ __launch_bounds__(256, 4) void attn_mfma(const unsigned short* __restrict__ Qb,
                                                    const unsigned short* __restrict__ KVb,
                                                    const unsigned short* __restrict__ VTb,
                                                    unsigned short* __restrict__ ctxB) {
  __shared__ unsigned short smem[12288]; // 24576 B
  unsigned short* Ks = smem;             // [64 key][64 d] swz
  unsigned short* Vts = smem + 4096;     // [64 d][64 key] swz
  unsigned short* Ps = smem + 8192;      // 4 waves x [16 q][64 key] swz
  const int tid = threadIdx.x;
  const int wave = tid >> 6, lane = tid & 63;
  const int ln = lane & 15, quad = lane >> 4;
  // XCD-affinity decode (all 16 pair-blocks of one (b,h) on one XCD)
  const int hw = blockIdx.x;              // 0..1023
  const int xcd = hw & 7, slot = hw >> 3; // slot 0..127
  const int grp = xcd * 8 + (slot >> 4);  // 0..63 = (b,h) group
  const int pair = slot & 15;             // 0..15
  const int h = grp & 15, b = grp >> 4;
  const int tA = pair, tB = 31 - pair;    // 64-row q-tile indices, tB > tA
  const int s0A = tA * 64, s0B = tB * 64;
  const int ktmaxB = tB;                  // inclusive
  const int qminA = s0A + wave * 16, qmaxA = qminA + 15;
  const int qminB = s0B + wave * 16, qmaxB = qminB + 15;

  short8 qfA[2], qfB[2]; // B-operand: rows = q
  {
    const unsigned short* qa =
        Qb + (size_t)(b * SS + s0A + wave * 16 + ln) * DIM + h * HD + quad * 8;
    qfA[0] = *(const short8*)qa;
    qfA[1] = *(const short8*)(qa + 32);
    const unsigned short* qb2 =
        Qb + (size_t)(b * SS + s0B + wave * 16 + ln) * DIM + h * HD + quad * 8;
    qfB[0] = *(const short8*)qb2;
    qfB[1] = *(const short8*)(qb2 + 32);
  }

  f32x4 ocA[4], ocB[4]; // PV acc: row q=quad*4+r, col d=dt*16+ln
  float lpA = 0.f, lpB = 0.f;
#pragma unroll
  for (int i = 0; i < 4; i++) {
    ocA[i] = (f32x4){0.f, 0.f, 0.f, 0.f};
    ocB[i] = (f32x4){0.f, 0.f, 0.f, 0.f};
  }

  unsigned short* Pw = Ps + wave * (16 * 64);
  const int swz = (ln & 7) << 3; // read-side XOR (shorts); row&7 == ln&7

  const int srow = tid >> 3, sc8 = (tid & 7) * 8; // 32 rows per shot
  const int ssc = sc8 ^ ((srow & 7) << 3);        // write-side XOR (shorts)

  const unsigned short* kptr =
      KVb + (size_t)(b * SS + srow) * (2 * DIM) + h * HD + sc8;
  const unsigned short* vptr = VTb + (size_t)(b * DIM + h * HD + srow) * SS + sc8;
  const size_t kstep = (size_t)64 * 2 * DIM;
  const size_t krow32 = (size_t)32 * 2 * DIM;
  const size_t vrow32 = (size_t)32 * SS;

  short8 kreg0 = *(const short8*)kptr;
  short8 kreg1 = *(const short8*)(kptr + krow32);
  short8 vreg0 = *(const short8*)vptr;
  short8 vreg1 = *(const short8*)(vptr + vrow32);

  for (int kt = 0; kt <= ktmaxB; ++kt) {
    __syncthreads(); // prior-iter LDS readers done
    *(short8*)(Ks + srow * 64 + ssc) = kreg0;
    *(short8*)(Ks + (srow + 32) * 64 + ssc) = kreg1;
    *(short8*)(Vts + srow * 64 + ssc) = vreg0;
    *(short8*)(Vts + (srow + 32) * 64 + ssc) = vreg1;
    __syncthreads();
    if (kt < ktmaxB) { // prefetch next K/V tile (overlaps compute)
      kptr += kstep; vptr += 64;
      kreg0 = *(const short8*)kptr;
      kreg1 = *(const short8*)(kptr + krow32);
      vreg0 = *(const short8*)vptr;
      vreg1 = *(const short8*)(vptr + vrow32);
    }

    const int k0g = kt * 64;

    auto stream = [&](const short8* qf, f32x4* oc, float& lp, const int qminw,
                      const int qmaxw) {
      if (k0g > qmaxw) return; // whole tile masked for this wave (wave-uniform)
      const bool needmask = (k0g + 63 > qminw);

      f32x4 sacc[4]; // S^T: nt -> keys k0g+nt*16+quad*4+r, col q=ln
#pragma unroll
      for (int nt = 0; nt < 4; nt++) sacc[nt] = (f32x4){0.f, 0.f, 0.f, 0.f};
      __builtin_amdgcn_s_setprio(1);
#pragma unroll
      for (int kc = 0; kc < 2; kc++) {
        const int rc = (kc * 32 + quad * 8) ^ swz;
#pragma unroll
        for (int nt = 0; nt < 4; nt++) {
          if (k0g + nt * 16 > qmaxw) continue; // strip fully masked
          short8 kfrag = *(const short8*)(Ks + (nt * 16 + ln) * 64 + rc);
          sacc[nt] =
              __builtin_amdgcn_mfma_f32_16x16x32_bf16(kfrag, qf[kc], sacc[nt], 0, 0, 0);
        }
      }
      __builtin_amdgcn_s_setprio(0);

      // Fixed-max softmax (scale pre-baked into Q): interior path has no
      // per-element masking VALU at all.
      const int qg = qminw + ln; // this thread's q column (global)
      float lt = 0.f;
      if (!needmask) {
#pragma unroll
        for (int nt = 0; nt < 4; nt++) {
          float p0 = __builtin_exp2f(sacc[nt][0]);
          float p1 = __builtin_exp2f(sacc[nt][1]);
          float p2 = __builtin_exp2f(sacc[nt][2]);
          float p3 = __builtin_exp2f(sacc[nt][3]);
          uint2 pw;
          pw.x = pack_bf16_pair(p0, p1);
          pw.y = pack_bf16_pair(p2, p3);
          *(uint2*)(Pw + ln * 64 + ((nt * 16 + quad * 4) ^ swz)) = pw;
          lt += (p0 + p1) + (p2 + p3);
        }
      } else {
#pragma unroll
        for (int nt = 0; nt < 4; nt++) {
          const int base = k0g + nt * 16 + quad * 4;
          float pe[4];
#pragma unroll
          for (int r = 0; r < 4; r++) {
            float p = __builtin_exp2f(sacc[nt][r]);
            if (base + r > qg) p = 0.f;
            pe[r] = p;
          }
          uint2 pw;
          pw.x = pack_bf16_pair(pe[0], pe[1]);
          pw.y = pack_bf16_pair(pe[2], pe[3]);
          *(uint2*)(Pw + ln * 64 + ((nt * 16 + quad * 4) ^ swz)) = pw;
          lt += (pe[0] + pe[1]) + (pe[2] + pe[3]);
        }
      }
      lp += lt;

      __builtin_amdgcn_s_setprio(1);
#pragma unroll
      for (int kc = 0; kc < 2; kc++) {
        if (k0g + kc * 32 > qmaxw) continue; // P chunk all zero
        const int rc = (kc * 32 + quad * 8) ^ swz;
        short8 pfrag = *(const short8*)(Pw + ln * 64 + rc);
#pragma unroll
        for (int dt = 0; dt < 4; dt++) {
          short8 vfrag = *(const short8*)(Vts + (dt * 16 + ln) * 64 + rc);
          oc[dt] =
              __builtin_amdgcn_mfma_f32_16x16x32_bf16(pfrag, vfrag, oc[dt], 0, 0, 0);
        }
      }
      __builtin_amdgcn_s_setprio(0);
    };

    stream(qfA, ocA, lpA, qminA, qmaxA);
    stream(qfB, ocB, lpB, qminB, qmaxB);
  }

  // Denominators: reduce across the 4 quads, broadcast to owned rows.
  lpA += __shfl_xor(lpA, 16, 64);
  lpA += __shfl_xor(lpA, 32, 64);
  lpB += __shfl_xor(lpB, 16, 64);
  lpB += __shfl_xor(lpB, 32, 64);
  float liA[4], liB[4];
#pragma unroll
  for (int r = 0; r < 4; r++) {
    liA[r] = 1.f / __shfl(lpA, quad * 4 + r, 64);
    liB[r] = 1.f / __shfl(lpB, quad * 4 + r, 64);
  }

  // Epilogue: normalize, stage each 64x64 tile through smem, 16B stores.
  __syncthreads();
#pragma unroll
  for (int r = 0; r < 4; r++) {
#pragma unroll
    for (int dt = 0; dt < 4; dt++)
      smem[(wave * 16 + quad * 4 + r) * 72 + dt * 16 + ln] = f2b(ocA[dt][r] * liA[r]);
  }
  __syncthreads();
#pragma unroll
  for (int t = 0; t < 2; ++t) {
    int idx = tid + t * 256;
    int row = idx >> 3, c = idx & 7;
    short8 v = *(const short8*)(smem + row * 72 + c * 8);
    *(short8*)(ctxB + (size_t)(b * SS + s0A + row) * DIM + h * HD + c * 8) = v;
  }
  __syncthreads();
#pragma unroll
  for (int r = 0; r < 4; r++) {
#pragma unroll
    for (int dt = 0; dt < 4; dt++)
      smem[(wave * 16 + quad * 4 + r) * 72 + dt * 16 + ln] = f2b(ocB[dt][r] * liB[r]);
  }
  __syncthreads();
#pragma unroll
  for (int t = 0; t < 2; ++t) {
    int idx = tid + t * 256;
    int row = idx >> 3, c = idx & 7;
    short8 v = *(const short8*)(smem + row * 72 + c * 8);
    *(short8*)(ctxB + (size_t)(b * SS + s0B + row) * DIM + h * HD + c * 8) = v;
  }
}

extern "C" void kernel_launch(void* const* d_in, const int* in_sizes, int n_in,
                              void* d_out, int out_size, void* d_ws, size_t ws_size,
                              hipStream_t stream) {
  const float* x     = (const float*)d_in[0];
  const float* w_kvc = (const float*)d_in[2];
  const float* b_kvc = (const float*)d_in[3];
  const float* w_kvu = (const float*)d_in[4];
  const float* b_kvu = (const float*)d_in[5];
  const float* w_qc  = (const float*)d_in[6];
  const float* b_qc  = (const float*)d_in[7];
  const float* w_qu  = (const float*)d_in[8];
  const float* b_qu  = (const float*)d_in[9];
  const float* w_o   = (const float*)d_in[10];
  const float* b_o   = (const float*)d_in[11];
  float* out = (float*)d_out;

  unsigned short* xb     = (unsigned short*)d_ws;          // [BS][DIM]; reused as VT
  unsigned short* wcatT  = xb + (size_t)BS * DIM;          // [NCAT][DIM]
  unsigned short* wkvuT  = wcatT + (size_t)NCAT * DIM;     // [2*DIM][LAT]
  unsigned short* wquT   = wkvuT + (size_t)LAT * 2 * DIM;  // [DIM][QR]
  unsigned short* woT    = wquT + (size_t)QR * DIM;        // [DIM][DIM]
  unsigned short* kvqlat = woT + (size_t)DIM * DIM;        // [BS][NCAT] (kv | q)
  unsigned short* kvup   = kvqlat + (size_t)BS * NCAT;     // [BS][2*DIM] (K | dead V)
  unsigned short* Qbuf   = kvup + (size_t)BS * 2 * DIM;    // [BS][DIM]
  unsigned short* ctx    = Qbuf + (size_t)BS * DIM;        // [BS][DIM]
  float* bias_cat        = (float*)(ctx + (size_t)BS * DIM); // [NCAT]

  // fused convert + weight prep (one launch)
  cvt_prep<<<8673, 256, 0, stream>>>(x, xb, w_kvc, w_qc, w_kvu, w_qu, w_o,
                                     b_kvc, b_qc, wcatT, wkvuT, wquT, woT,
                                     bias_cat);

  // stage-1: [kvlat | qlat] = x @ [w_kvc | w_qc]   (8192x384x1024), 384 blocks
  gemm_lds<<<384, 256, 0, stream>>>(xb, wcatT, bias_cat, nullptr, kvqlat,
                                    nullptr, NCAT, DIM, DIM, NCAT, 1.0f, 384);
  unsigned short* VT = xb; // xb dead after stage-1
  // fused stage-2 (8192x2048x128, V written transposed to VT) + Q-path
  // (8192x1024x256, softmax scale baked in): 3072 blocks
  gemm_s2q<<<3072, 256, 0, stream>>>(kvqlat, wkvuT, wquT, b_kvu, b_qu, kvup,
                                     VT, Qbuf);
  attn_mfma<<<1024, 256, 0, stream>>>(Qbuf, kvup, VT, ctx);
  // O-proj (8192x1024x1024), 1024 blocks
  gemm_lds<<<1024, 256, 0, stream>>>(ctx, woT, b_o, out, nullptr, nullptr,
                                     DIM, DIM, DIM, DIM, 1.0f, 1024);
}

// Round 11
// 248.059 us; speedup vs baseline: 1.0327x; 1.0086x over previous
//
#include <hip/hip_runtime.h>

typedef __attribute__((ext_vector_type(8))) short short8;
typedef __attribute__((ext_vector_type(4))) float f32x4;

#define DIM 1024
#define NH 16
#define HD 64
#define LAT 128
#define QR 256
#define NCAT (LAT + QR) /* 384 */
#define BB 4
#define SS 2048
#define BS (BB * SS) /* 8192 */

// exp(s*0.125) == exp2(s * 0.125*log2(e)); baked into Q at the GEMM epilogue.
#define SCALE_LOG2E 0.18033688011112042f

__device__ __forceinline__ unsigned short f2b(float f) {
  unsigned int u = __builtin_bit_cast(unsigned int, f);
  u += 0x7FFFu + ((u >> 16) & 1u); // RNE
  return (unsigned short)(u >> 16);
}
__device__ __forceinline__ float b2f(unsigned short h) {
  unsigned int u = ((unsigned int)h) << 16;
  return __builtin_bit_cast(float, u);
}
// 2x f32 -> packed bf16 in ONE VALU op (v_cvt_pk_bf16_f32, RNE). lo16 =
// cvt(f0), hi16 = cvt(f1). Replaces the 3-op add/add/perm pack (T12 primitive).
__device__ __forceinline__ unsigned int cvtpk_bf16(float f0, float f1) {
  unsigned int r;
  asm("v_cvt_pk_bf16_f32 %0, %1, %2" : "=v"(r) : "v"(f0), "v"(f1));
  return r;
}
// async global->LDS, 16B per lane. LDS dest is wave-uniform base + lane*16.
__device__ __forceinline__ void gll16(const unsigned short* g, unsigned short* l) {
  __builtin_amdgcn_global_load_lds(
      (const __attribute__((address_space(1))) unsigned int*)g,
      (__attribute__((address_space(3))) unsigned int*)l, 16, 0, 0);
}

// Fused: x f32->bf16 convert (blocks 0..8191) + all 5 weight transposes +
// bias concat (blocks 8192..8672). One launch.
__global__ __launch_bounds__(256) void cvt_prep(
    const float* __restrict__ x, unsigned short* __restrict__ xb,
    const float* __restrict__ w_kvc, const float* __restrict__ w_qc,
    const float* __restrict__ w_kvu, const float* __restrict__ w_qu,
    const float* __restrict__ w_o, const float* __restrict__ b_kvc,
    const float* __restrict__ b_qc, unsigned short* __restrict__ wcatT,
    unsigned short* __restrict__ wkvuT, unsigned short* __restrict__ wquT,
    unsigned short* __restrict__ woT, float* __restrict__ bias_cat) {
  __shared__ unsigned short T[64 * 72];
  const int tid = threadIdx.x;
  if (blockIdx.x < 8192) { // cvt_x: 8192*256*4 = BS*DIM elements
    int i = blockIdx.x * 256 + tid;
    f32x4 v = ((const f32x4*)x)[i];
    ushort4 o;
    o.x = f2b(v[0]); o.y = f2b(v[1]); o.z = f2b(v[2]); o.w = f2b(v[3]);
    ((ushort4*)xb)[i] = o;
    return;
  }
  const int id = blockIdx.x - 8192;
  if (id >= 480) { // bias concat (384 floats)
    if (tid < LAT) bias_cat[tid] = b_kvc[tid];
    else bias_cat[tid] = b_qc[tid - LAT];
    if (tid < 128) bias_cat[tid + 256] = b_qc[tid + 128];
    return;
  }
  const float* in; unsigned short* out; int K, N, tile;
  if (id < 32)       { in = w_kvc; out = wcatT;                       K = DIM; N = LAT;     tile = id; }
  else if (id < 96)  { in = w_qc;  out = wcatT + (size_t)LAT * DIM;   K = DIM; N = QR;      tile = id - 32; }
  else if (id < 160) { in = w_kvu; out = wkvuT;                       K = LAT; N = 2 * DIM; tile = id - 96; }
  else if (id < 224) { in = w_qu;  out = wquT;                        K = QR;  N = DIM;     tile = id - 160; }
  else               { in = w_o;   out = woT;                         K = DIM; N = DIM;     tile = id - 224; }
  const int ktiles = K >> 6;
  const int k0 = (tile % ktiles) * 64, n0 = (tile / ktiles) * 64;
  {
    const int r = tid >> 2, cq = (tid & 3) * 16;
#pragma unroll
    for (int j = 0; j < 4; ++j) {
      f32x4 v = *(const f32x4*)(in + (size_t)(k0 + r) * N + n0 + cq + j * 4);
      ushort4 o;
      o.x = f2b(v[0]); o.y = f2b(v[1]); o.z = f2b(v[2]); o.w = f2b(v[3]);
      *(ushort4*)(T + r * 72 + cq + j * 4) = o;
    }
  }
  __syncthreads();
#pragma unroll
  for (int s = 0; s < 2; ++s) {
    int idx = tid + s * 256;
    int nr = idx >> 3, kg = (idx & 7) * 8;
    short8 o;
#pragma unroll
    for (int i = 0; i < 8; i++) o[i] = T[(kg + i) * 72 + nr];
    *(short8*)(out + (size_t)(n0 + nr) * K + k0 + kg) = o;
  }
}

// GEMM body, BM=64 x BN=128 (4 blocks/CU) + 3-deep ring with counted vmcnt
// (lookahead-2): per step {vmcnt(3) -> lgkmcnt(0) -> barrier -> issue
// STAGE(t+2) -> ds_read + MFMA}. Source-side conflict swizzle (rule #21).
// LDS 36 KB. vtOut: blocks with n0 >= DIM write tile transposed.
// (R7-R10: schedule variants all neutral; structure kept as-is.)
__device__ __forceinline__ void gemm_body(
    const unsigned short* __restrict__ A, const unsigned short* __restrict__ WT,
    const float* __restrict__ bias, float* __restrict__ outF,
    unsigned short* __restrict__ outB, unsigned short* __restrict__ vtOut,
    int N, int K, int lda, int ldout, float scale, int nblk, int bid,
    unsigned short* gsm) {
  const int tid = threadIdx.x;
  const int wave = tid >> 6, lane = tid & 63;
  const int ln = lane & 15, quad = lane >> 4;
  const int chunk = nblk >> 3;
  const int sw = (bid & 7) * chunk + (bid >> 3); // XCD-chunked swizzle (T1)
  const int nwx = N >> 7;
  const int bx = sw % nwx, by = sw / nwx;
  const int m0 = by * 64, n0 = bx * 128;
  const int wm = (wave >> 1) * 32, wn = (wave & 1) * 64;

  // staging: A rows wave*16..+15 (1 gll), B rows wave*32..+31 (2 glls).
  // global source col pre-swizzled cg^(row&3); LDS dest linear.
  const int sr = lane >> 2;
  const int scg = (lane & 3) ^ (sr & 3);
  const unsigned short* Ag = A + (size_t)(m0 + wave * 16 + sr) * lda + scg * 8;
  const unsigned short* Bg = WT + (size_t)(n0 + wave * 32 + sr) * K + scg * 8;

  f32x4 acc[2][4];
#pragma unroll
  for (int i = 0; i < 2; i++)
#pragma unroll
    for (int j = 0; j < 4; j++) acc[i][j] = (f32x4){0.f, 0.f, 0.f, 0.f};

  // A ring: 3 x 2048 shorts at gsm[0..6144); B ring: 3 x 4096 at gsm[6144..)
#define STAGE(buf, kk)                                                        \
  {                                                                           \
    unsigned short* Al = gsm + (buf) * 2048 + wave * 512;                     \
    unsigned short* Bl = gsm + 6144 + (buf) * 4096 + wave * 1024;             \
    gll16(Ag + (kk), Al);                                                     \
    gll16(Bg + (kk), Bl);                                                     \
    gll16(Bg + (size_t)16 * K + (kk), Bl + 512);                              \
  }

  const int T = K >> 5; // >= 4 at all call sites
  STAGE(0, 0);
  STAGE(1, 32);

  const int rc = (quad ^ (ln & 3)) * 8; // swizzled fragment col (shorts)
  for (int t = 0; t < T; ++t) {
    // stage-t completion: outstanding = stages {t, t+1} (6 loads) except at
    // t==T-1 where only stage t (3 loads) remains.
    if (t + 1 < T) asm volatile("s_waitcnt vmcnt(3)" ::: "memory");
    else           asm volatile("s_waitcnt vmcnt(0)" ::: "memory");
    asm volatile("s_waitcnt lgkmcnt(0)" ::: "memory"); // prior reads consumed
    __builtin_amdgcn_s_barrier();
    if (t + 2 < T) {
      const int nb = (t + 2) % 3;
      STAGE(nb, (t + 2) * 32);
    }
    const unsigned short* Ab = gsm + (t % 3) * 2048;
    const unsigned short* Bb = gsm + 6144 + (t % 3) * 4096;
    short8 af[2], bf[4];
#pragma unroll
    for (int i = 0; i < 2; i++)
      af[i] = *(const short8*)(Ab + (wm + i * 16 + ln) * 32 + rc);
#pragma unroll
    for (int i = 0; i < 4; i++)
      bf[i] = *(const short8*)(Bb + (wn + i * 16 + ln) * 32 + rc);
#pragma unroll
    for (int mi = 0; mi < 2; mi++)
#pragma unroll
      for (int ni = 0; ni < 4; ni++)
        acc[mi][ni] =
            __builtin_amdgcn_mfma_f32_16x16x32_bf16(af[mi], bf[ni], acc[mi][ni], 0, 0, 0);
  }
#undef STAGE

  if (vtOut && n0 >= DIM) {
    // Fused V-transpose: stage 64s x 128d tile transposed, write VT rows.
    __syncthreads(); // all waves done with ring reads before gsm reuse
#pragma unroll
    for (int mi = 0; mi < 2; mi++) {
      const int s = wm + mi * 16 + quad * 4;
#pragma unroll
      for (int ni = 0; ni < 4; ni++) {
        const int d = wn + ni * 16 + ln;
        const float bv = bias[n0 + d];
#pragma unroll
        for (int r = 0; r < 4; r++)
          gsm[d * 72 + s + r] = f2b(acc[mi][ni][r] + bv);
      }
    }
    __syncthreads();
    const int d0 = n0 - DIM, bb = m0 >> 11, s0l = m0 & (SS - 1);
#pragma unroll
    for (int t = 0; t < 4; ++t) {
      int idx = tid + t * 256;
      int dr = idx >> 3, cs = (idx & 7) * 8;
      short8 v = *(const short8*)(gsm + dr * 72 + cs);
      *(short8*)(vtOut + (size_t)(bb * DIM + d0 + dr) * SS + s0l + cs) = v;
    }
    return;
  }

#pragma unroll
  for (int mi = 0; mi < 2; mi++) {
    const int row = m0 + wm + mi * 16 + quad * 4;
#pragma unroll
    for (int ni = 0; ni < 4; ni++) {
      const int col = n0 + wn + ni * 16 + ln;
      const float bv = bias[col];
#pragma unroll
      for (int r = 0; r < 4; r++) {
        float v = (acc[mi][ni][r] + bv) * scale;
        size_t o = (size_t)(row + r) * ldout + col;
        if (outF) outF[o] = v;
        if (outB) outB[o] = f2b(v);
      }
    }
  }
}

__global__ __launch_bounds__(256, 4) void gemm_lds(const unsigned short* __restrict__ A,
                                                   const unsigned short* __restrict__ WT,
                                                   const float* __restrict__ bias,
                                                   float* __restrict__ outF,
                                                   unsigned short* __restrict__ outB,
                                                   unsigned short* __restrict__ vtOut,
                                                   int N, int K, int lda, int ldout,
                                                   float scale, int nblk) {
  __shared__ unsigned short gsm[18432]; // 36864 B: ring 3x(A 4KB + B 8KB)
  gemm_body(A, WT, bias, outF, outB, vtOut, N, K, lda, ldout, scale, nblk,
            blockIdx.x, gsm);
}

// Fused stage-2 + Q-path (both read kvqlat, mutually independent): blocks
// 0..2047 = stage-2 (N=2048, K=128, fused V-transpose), 2048..3071 = Q-path
// (N=1024, K=256, softmax scale baked in). Tails overlap; one launch gap gone.
__global__ __launch_bounds__(256, 4) void gemm_s2q(
    const unsigned short* __restrict__ kvqlat, const unsigned short* __restrict__ wkvuT,
    const unsigned short* __restrict__ wquT, const float* __restrict__ b_kvu,
    const float* __restrict__ b_qu, unsigned short* __restrict__ kvup,
    unsigned short* __restrict__ VT, unsigned short* __restrict__ Qbuf) {
  __shared__ unsigned short gsm[18432];
  if (blockIdx.x < 2048)
    gemm_body(kvqlat, wkvuT, b_kvu, nullptr, kvup, VT, 2 * DIM, LAT, NCAT,
              2 * DIM, 1.0f, 2048, blockIdx.x, gsm);
  else
    gemm_body(kvqlat + LAT, wquT, b_qu, nullptr, Qbuf, nullptr, DIM, QR, NCAT,
              DIM, SCALE_LOG2E, 1024, blockIdx.x - 2048, gsm);
}

// MFMA flash attention, causal, fixed-max softmax, S^T orientation.
// Structure frozen (sequential streams, antidiagonal pairing, XCD-affinity,
// XOR swizzle). THIS ROUND: softmax P-packing via v_cvt_pk_bf16_f32 (1 VALU
// op per bf16 pair, was 3 via add/add/perm) — VALU was 56% busy and the
// softmax stream is attn's largest VALU component after exp2.
__global__ __launch_bounds__(256, 4) void attn_mfma(const unsigned short* __restrict__ Qb,
                                                    const unsigned short* __restrict__ KVb,
                                                    const unsigned short* __restrict__ VTb,
                                                    unsigned short* __restrict__ ctxB) {
  __shared__ unsigned short smem[12288]; // 24576 B
  unsigned short* Ks = smem;             // [64 key][64 d] swz
  unsigned short* Vts = smem + 4096;     // [64 d][64 key] swz
  unsigned short* Ps = smem + 8192;      // 4 waves x [16 q][64 key] swz
  const int tid = threadIdx.x;
  const int wave = tid >> 6, lane = tid & 63;
  const int ln = lane & 15, quad = lane >> 4;
  // XCD-affinity decode (all 16 pair-blocks of one (b,h) on one XCD)
  const int hw = blockIdx.x;              // 0..1023
  const int xcd = hw & 7, slot = hw >> 3; // slot 0..127
  const int grp = xcd * 8 + (slot >> 4);  // 0..63 = (b,h) group
  const int pair = slot & 15;             // 0..15
  const int h = grp & 15, b = grp >> 4;
  const int tA = pair, tB = 31 - pair;    // 64-row q-tile indices, tB > tA
  const int s0A = tA * 64, s0B = tB * 64;
  const int ktmaxB = tB;                  // inclusive
  const int qminA = s0A + wave * 16, qmaxA = qminA + 15;
  const int qminB = s0B + wave * 16, qmaxB = qminB + 15;

  short8 qfA[2], qfB[2]; // B-operand: rows = q
  {
    const unsigned short* qa =
        Qb + (size_t)(b * SS + s0A + wave * 16 + ln) * DIM + h * HD + quad * 8;
    qfA[0] = *(const short8*)qa;
    qfA[1] = *(const short8*)(qa + 32);
    const unsigned short* qb2 =
        Qb + (size_t)(b * SS + s0B + wave * 16 + ln) * DIM + h * HD + quad * 8;
    qfB[0] = *(const short8*)qb2;
    qfB[1] = *(const short8*)(qb2 + 32);
  }

  f32x4 ocA[4], ocB[4]; // PV acc: row q=quad*4+r, col d=dt*16+ln
  float lpA = 0.f, lpB = 0.f;
#pragma unroll
  for (int i = 0; i < 4; i++) {
    ocA[i] = (f32x4){0.f, 0.f, 0.f, 0.f};
    ocB[i] = (f32x4){0.f, 0.f, 0.f, 0.f};
  }

  unsigned short* Pw = Ps + wave * (16 * 64);
  const int swz = (ln & 7) << 3; // read-side XOR (shorts); row&7 == ln&7

  const int srow = tid >> 3, sc8 = (tid & 7) * 8; // 32 rows per shot
  const int ssc = sc8 ^ ((srow & 7) << 3);        // write-side XOR (shorts)

  const unsigned short* kptr =
      KVb + (size_t)(b * SS + srow) * (2 * DIM) + h * HD + sc8;
  const unsigned short* vptr = VTb + (size_t)(b * DIM + h * HD + srow) * SS + sc8;
  const size_t kstep = (size_t)64 * 2 * DIM;
  const size_t krow32 = (size_t)32 * 2 * DIM;
  const size_t vrow32 = (size_t)32 * SS;

  short8 kreg0 = *(const short8*)kptr;
  short8 kreg1 = *(const short8*)(kptr + krow32);
  short8 vreg0 = *(const short8*)vptr;
  short8 vreg1 = *(const short8*)(vptr + vrow32);

  for (int kt = 0; kt <= ktmaxB; ++kt) {
    __syncthreads(); // prior-iter LDS readers done
    *(short8*)(Ks + srow * 64 + ssc) = kreg0;
    *(short8*)(Ks + (srow + 32) * 64 + ssc) = kreg1;
    *(short8*)(Vts + srow * 64 + ssc) = vreg0;
    *(short8*)(Vts + (srow + 32) * 64 + ssc) = vreg1;
    __syncthreads();
    if (kt < ktmaxB) { // prefetch next K/V tile (overlaps compute)
      kptr += kstep; vptr += 64;
      kreg0 = *(const short8*)kptr;
      kreg1 = *(const short8*)(kptr + krow32);
      vreg0 = *(const short8*)vptr;
      vreg1 = *(const short8*)(vptr + vrow32);
    }

    const int k0g = kt * 64;

    auto stream = [&](const short8* qf, f32x4* oc, float& lp, const int qminw,
                      const int qmaxw) {
      if (k0g > qmaxw) return; // whole tile masked for this wave (wave-uniform)
      const bool needmask = (k0g + 63 > qminw);

      f32x4 sacc[4]; // S^T: nt -> keys k0g+nt*16+quad*4+r, col q=ln
#pragma unroll
      for (int nt = 0; nt < 4; nt++) sacc[nt] = (f32x4){0.f, 0.f, 0.f, 0.f};
      __builtin_amdgcn_s_setprio(1);
#pragma unroll
      for (int kc = 0; kc < 2; kc++) {
        const int rc = (kc * 32 + quad * 8) ^ swz;
#pragma unroll
        for (int nt = 0; nt < 4; nt++) {
          if (k0g + nt * 16 > qmaxw) continue; // strip fully masked
          short8 kfrag = *(const short8*)(Ks + (nt * 16 + ln) * 64 + rc);
          sacc[nt] =
              __builtin_amdgcn_mfma_f32_16x16x32_bf16(kfrag, qf[kc], sacc[nt], 0, 0, 0);
        }
      }
      __builtin_amdgcn_s_setprio(0);

      // Fixed-max softmax (scale pre-baked into Q): interior path has no
      // per-element masking VALU; P packed via v_cvt_pk_bf16_f32.
      const int qg = qminw + ln; // this thread's q column (global)
      float lt = 0.f;
      if (!needmask) {
#pragma unroll
        for (int nt = 0; nt < 4; nt++) {
          float p0 = __builtin_exp2f(sacc[nt][0]);
          float p1 = __builtin_exp2f(sacc[nt][1]);
          float p2 = __builtin_exp2f(sacc[nt][2]);
          float p3 = __builtin_exp2f(sacc[nt][3]);
          uint2 pw;
          pw.x = cvtpk_bf16(p0, p1);
          pw.y = cvtpk_bf16(p2, p3);
          *(uint2*)(Pw + ln * 64 + ((nt * 16 + quad * 4) ^ swz)) = pw;
          lt += (p0 + p1) + (p2 + p3);
        }
      } else {
#pragma unroll
        for (int nt = 0; nt < 4; nt++) {
          const int base = k0g + nt * 16 + quad * 4;
          float pe[4];
#pragma unroll
          for (int r = 0; r < 4; r++) {
            float p = __builtin_exp2f(sacc[nt][r]);
            if (base + r > qg) p = 0.f;
            pe[r] = p;
          }
          uint2 pw;
          pw.x = cvtpk_bf16(pe[0], pe[1]);
          pw.y = cvtpk_bf16(pe[2], pe[3]);
          *(uint2*)(Pw + ln * 64 + ((nt * 16 + quad * 4) ^ swz)) = pw;
          lt += (pe[0] + pe[1]) + (pe[2] + pe[3]);
        }
      }
      lp += lt;

      __builtin_amdgcn_s_setprio(1);
#pragma unroll
      for (int kc = 0; kc < 2; kc++) {
        if (k0g + kc * 32 > qmaxw) continue; // P chunk all zero
        const int rc = (kc * 32 + quad * 8) ^ swz;
        short8 pfrag = *(const short8*)(Pw + ln * 64 + rc);
#pragma unroll
        for (int dt = 0; dt < 4; dt++) {
          short8 vfrag = *(const short8*)(Vts + (dt * 16 + ln) * 64 + rc);
          oc[dt] =
              __builtin_amdgcn_mfma_f32_16x16x32_bf16(pfrag, vfrag, oc[dt], 0, 0, 0);
        }
      }
      __builtin_amdgcn_s_setprio(0);
    };

    stream(qfA, ocA, lpA, qminA, qmaxA);
    stream(qfB, ocB, lpB, qminB, qmaxB);
  }

  // Denominators: reduce across the 4 quads, broadcast to owned rows.
  lpA += __shfl_xor(lpA, 16, 64);
  lpA += __shfl_xor(lpA, 32, 64);
  lpB += __shfl_xor(lpB, 16, 64);
  lpB += __shfl_xor(lpB, 32, 64);
  float liA[4], liB[4];
#pragma unroll
  for (int r = 0; r < 4; r++) {
    liA[r] = 1.f / __shfl(lpA, quad * 4 + r, 64);
    liB[r] = 1.f / __shfl(lpB, quad * 4 + r, 64);
  }

  // Epilogue: normalize, stage each 64x64 tile through smem, 16B stores.
  __syncthreads();
#pragma unroll
  for (int r = 0; r < 4; r++) {
#pragma unroll
    for (int dt = 0; dt < 4; dt++)
      smem[(wave * 16 + quad * 4 + r) * 72 + dt * 16 + ln] = f2b(ocA[dt][r] * liA[r]);
  }
  __syncthreads();
#pragma unroll
  for (int t = 0; t < 2; ++t) {
    int idx = tid + t * 256;
    int row = idx >> 3, c = idx & 7;
    short8 v = *(const short8*)(smem + row * 72 + c * 8);
    *(short8*)(ctxB + (size_t)(b * SS + s0A + row) * DIM + h * HD + c * 8) = v;
  }
  __syncthreads();
#pragma unroll
  for (int r = 0; r < 4; r++) {
#pragma unroll
    for (int dt = 0; dt < 4; dt++)
      smem[(wave * 16 + quad * 4 + r) * 72 + dt * 16 + ln] = f2b(ocB[dt][r] * liB[r]);
  }
  __syncthreads();
#pragma unroll
  for (int t = 0; t < 2; ++t) {
    int idx = tid + t * 256;
    int row = idx >> 3, c = idx & 7;
    short8 v = *(const short8*)(smem + row * 72 + c * 8);
    *(short8*)(ctxB + (size_t)(b * SS + s0B + row) * DIM + h * HD + c * 8) = v;
  }
}

extern "C" void kernel_launch(void* const* d_in, const int* in_sizes, int n_in,
                              void* d_out, int out_size, void* d_ws, size_t ws_size,
                              hipStream_t stream) {
  const float* x     = (const float*)d_in[0];
  const float* w_kvc = (const float*)d_in[2];
  const float* b_kvc = (const float*)d_in[3];
  const float* w_kvu = (const float*)d_in[4];
  const float* b_kvu = (const float*)d_in[5];
  const float* w_qc  = (const float*)d_in[6];
  const float* b_qc  = (const float*)d_in[7];
  const float* w_qu  = (const float*)d_in[8];
  const float* b_qu  = (const float*)d_in[9];
  const float* w_o   = (const float*)d_in[10];
  const float* b_o   = (const float*)d_in[11];
  float* out = (float*)d_out;

  unsigned short* xb     = (unsigned short*)d_ws;          // [BS][DIM]; reused as VT
  unsigned short* wcatT  = xb + (size_t)BS * DIM;          // [NCAT][DIM]
  unsigned short* wkvuT  = wcatT + (size_t)NCAT * DIM;     // [2*DIM][LAT]
  unsigned short* wquT   = wkvuT + (size_t)LAT * 2 * DIM;  // [DIM][QR]
  unsigned short* woT    = wquT + (size_t)QR * DIM;        // [DIM][DIM]
  unsigned short* kvqlat = woT + (size_t)DIM * DIM;        // [BS][NCAT] (kv | q)
  unsigned short* kvup   = kvqlat + (size_t)BS * NCAT;     // [BS][2*DIM] (K | dead V)
  unsigned short* Qbuf   = kvup + (size_t)BS * 2 * DIM;    // [BS][DIM]
  unsigned short* ctx    = Qbuf + (size_t)BS * DIM;        // [BS][DIM]
  float* bias_cat        = (float*)(ctx + (size_t)BS * DIM); // [NCAT]

  // fused convert + weight prep (one launch)
  cvt_prep<<<8673, 256, 0, stream>>>(x, xb, w_kvc, w_qc, w_kvu, w_qu, w_o,
                                     b_kvc, b_qc, wcatT, wkvuT, wquT, woT,
                                     bias_cat);

  // stage-1: [kvlat | qlat] = x @ [w_kvc | w_qc]   (8192x384x1024), 384 blocks
  gemm_lds<<<384, 256, 0, stream>>>(xb, wcatT, bias_cat, nullptr, kvqlat,
                                    nullptr, NCAT, DIM, DIM, NCAT, 1.0f, 384);
  unsigned short* VT = xb; // xb dead after stage-1
  // fused stage-2 (8192x2048x128, V written transposed to VT) + Q-path
  // (8192x1024x256, softmax scale baked in): 3072 blocks
  gemm_s2q<<<3072, 256, 0, stream>>>(kvqlat, wkvuT, wquT, b_kvu, b_qu, kvup,
                                     VT, Qbuf);
  attn_mfma<<<1024, 256, 0, stream>>>(Qbuf, kvup, VT, ctx);
  // O-proj (8192x1024x1024), 1024 blocks
  gemm_lds<<<1024, 256, 0, stream>>>(ctx, woT, b_o, out, nullptr, nullptr,
                                     DIM, DIM, DIM, DIM, 1.0f, 1024);
}

// Round 14
// 246.993 us; speedup vs baseline: 1.0372x; 1.0043x over previous
//
#include <hip/hip_runtime.h>

typedef __attribute__((ext_vector_type(8))) short short8;
typedef __attribute__((ext_vector_type(4))) float f32x4;

#define DIM 1024
#define NH 16
#define HD 64
#define LAT 128
#define QR 256
#define NCAT (LAT + QR) /* 384 */
#define BB 4
#define SS 2048
#define BS (BB * SS) /* 8192 */

// exp(s*0.125) == exp2(s * 0.125*log2(e)); baked into Q at the GEMM epilogue.
#define SCALE_LOG2E 0.18033688011112042f

__device__ __forceinline__ unsigned short f2b(float f) {
  unsigned int u = __builtin_bit_cast(unsigned int, f);
  u += 0x7FFFu + ((u >> 16) & 1u); // RNE
  return (unsigned short)(u >> 16);
}
__device__ __forceinline__ float b2f(unsigned short h) {
  unsigned int u = ((unsigned int)h) << 16;
  return __builtin_bit_cast(float, u);
}
// 2x f32 -> packed bf16 in ONE VALU op (v_cvt_pk_bf16_f32, RNE).
__device__ __forceinline__ unsigned int cvtpk_bf16(float f0, float f1) {
  unsigned int r;
  asm("v_cvt_pk_bf16_f32 %0, %1, %2" : "=v"(r) : "v"(f0), "v"(f1));
  return r;
}
// async global->LDS, 16B per lane. LDS dest is wave-uniform base + lane*16.
__device__ __forceinline__ void gll16(const unsigned short* g, unsigned short* l) {
  __builtin_amdgcn_global_load_lds(
      (const __attribute__((address_space(1))) unsigned int*)g,
      (__attribute__((address_space(3))) unsigned int*)l, 16, 0, 0);
}

// Fused: x f32->bf16 convert (blocks 0..8191) + all 5 weight transposes +
// bias concat (blocks 8192..8672). One launch.
__global__ __launch_bounds__(256) void cvt_prep(
    const float* __restrict__ x, unsigned short* __restrict__ xb,
    const float* __restrict__ w_kvc, const float* __restrict__ w_qc,
    const float* __restrict__ w_kvu, const float* __restrict__ w_qu,
    const float* __restrict__ w_o, const float* __restrict__ b_kvc,
    const float* __restrict__ b_qc, unsigned short* __restrict__ wcatT,
    unsigned short* __restrict__ wkvuT, unsigned short* __restrict__ wquT,
    unsigned short* __restrict__ woT, float* __restrict__ bias_cat) {
  __shared__ unsigned short T[64 * 72];
  const int tid = threadIdx.x;
  if (blockIdx.x < 8192) { // cvt_x: 8192*256*4 = BS*DIM elements
    int i = blockIdx.x * 256 + tid;
    f32x4 v = ((const f32x4*)x)[i];
    ushort4 o;
    o.x = f2b(v[0]); o.y = f2b(v[1]); o.z = f2b(v[2]); o.w = f2b(v[3]);
    ((ushort4*)xb)[i] = o;
    return;
  }
  const int id = blockIdx.x - 8192;
  if (id >= 480) { // bias concat (384 floats)
    if (tid < LAT) bias_cat[tid] = b_kvc[tid];
    else bias_cat[tid] = b_qc[tid - LAT];
    if (tid < 128) bias_cat[tid + 256] = b_qc[tid + 128];
    return;
  }
  const float* in; unsigned short* out; int K, N, tile;
  if (id < 32)       { in = w_kvc; out = wcatT;                       K = DIM; N = LAT;     tile = id; }
  else if (id < 96)  { in = w_qc;  out = wcatT + (size_t)LAT * DIM;   K = DIM; N = QR;      tile = id - 32; }
  else if (id < 160) { in = w_kvu; out = wkvuT;                       K = LAT; N = 2 * DIM; tile = id - 96; }
  else if (id < 224) { in = w_qu;  out = wquT;                        K = QR;  N = DIM;     tile = id - 160; }
  else               { in = w_o;   out = woT;                         K = DIM; N = DIM;     tile = id - 224; }
  const int ktiles = K >> 6;
  const int k0 = (tile % ktiles) * 64, n0 = (tile / ktiles) * 64;
  {
    const int r = tid >> 2, cq = (tid & 3) * 16;
#pragma unroll
    for (int j = 0; j < 4; ++j) {
      f32x4 v = *(const f32x4*)(in + (size_t)(k0 + r) * N + n0 + cq + j * 4);
      ushort4 o;
      o.x = f2b(v[0]); o.y = f2b(v[1]); o.z = f2b(v[2]); o.w = f2b(v[3]);
      *(ushort4*)(T + r * 72 + cq + j * 4) = o;
    }
  }
  __syncthreads();
#pragma unroll
  for (int s = 0; s < 2; ++s) {
    int idx = tid + s * 256;
    int nr = idx >> 3, kg = (idx & 7) * 8;
    short8 o;
#pragma unroll
    for (int i = 0; i < 8; i++) o[i] = T[(kg + i) * 72 + nr];
    *(short8*)(out + (size_t)(n0 + nr) * K + k0 + kg) = o;
  }
}

// GEMM body, BM=64 x BN=128 (4 blocks/CU) + 3-deep ring with counted vmcnt
// (lookahead-2). Source-side conflict swizzle (rule #21). LDS 36 KB.
// vtOut: blocks with n0 >= DIM write tile transposed. (Frozen since R10.)
__device__ __forceinline__ void gemm_body(
    const unsigned short* __restrict__ A, const unsigned short* __restrict__ WT,
    const float* __restrict__ bias, float* __restrict__ outF,
    unsigned short* __restrict__ outB, unsigned short* __restrict__ vtOut,
    int N, int K, int lda, int ldout, float scale, int nblk, int bid,
    unsigned short* gsm) {
  const int tid = threadIdx.x;
  const int wave = tid >> 6, lane = tid & 63;
  const int ln = lane & 15, quad = lane >> 4;
  const int chunk = nblk >> 3;
  const int sw = (bid & 7) * chunk + (bid >> 3); // XCD-chunked swizzle (T1)
  const int nwx = N >> 7;
  const int bx = sw % nwx, by = sw / nwx;
  const int m0 = by * 64, n0 = bx * 128;
  const int wm = (wave >> 1) * 32, wn = (wave & 1) * 64;

  const int sr = lane >> 2;
  const int scg = (lane & 3) ^ (sr & 3);
  const unsigned short* Ag = A + (size_t)(m0 + wave * 16 + sr) * lda + scg * 8;
  const unsigned short* Bg = WT + (size_t)(n0 + wave * 32 + sr) * K + scg * 8;

  f32x4 acc[2][4];
#pragma unroll
  for (int i = 0; i < 2; i++)
#pragma unroll
    for (int j = 0; j < 4; j++) acc[i][j] = (f32x4){0.f, 0.f, 0.f, 0.f};

#define STAGE(buf, kk)                                                        \
  {                                                                           \
    unsigned short* Al = gsm + (buf) * 2048 + wave * 512;                     \
    unsigned short* Bl = gsm + 6144 + (buf) * 4096 + wave * 1024;             \
    gll16(Ag + (kk), Al);                                                     \
    gll16(Bg + (kk), Bl);                                                     \
    gll16(Bg + (size_t)16 * K + (kk), Bl + 512);                              \
  }

  const int T = K >> 5; // >= 4 at all call sites
  STAGE(0, 0);
  STAGE(1, 32);

  const int rc = (quad ^ (ln & 3)) * 8; // swizzled fragment col (shorts)
  for (int t = 0; t < T; ++t) {
    if (t + 1 < T) asm volatile("s_waitcnt vmcnt(3)" ::: "memory");
    else           asm volatile("s_waitcnt vmcnt(0)" ::: "memory");
    asm volatile("s_waitcnt lgkmcnt(0)" ::: "memory"); // prior reads consumed
    __builtin_amdgcn_s_barrier();
    if (t + 2 < T) {
      const int nb = (t + 2) % 3;
      STAGE(nb, (t + 2) * 32);
    }
    const unsigned short* Ab = gsm + (t % 3) * 2048;
    const unsigned short* Bb = gsm + 6144 + (t % 3) * 4096;
    short8 af[2], bf[4];
#pragma unroll
    for (int i = 0; i < 2; i++)
      af[i] = *(const short8*)(Ab + (wm + i * 16 + ln) * 32 + rc);
#pragma unroll
    for (int i = 0; i < 4; i++)
      bf[i] = *(const short8*)(Bb + (wn + i * 16 + ln) * 32 + rc);
#pragma unroll
    for (int mi = 0; mi < 2; mi++)
#pragma unroll
      for (int ni = 0; ni < 4; ni++)
        acc[mi][ni] =
            __builtin_amdgcn_mfma_f32_16x16x32_bf16(af[mi], bf[ni], acc[mi][ni], 0, 0, 0);
  }
#undef STAGE

  if (vtOut && n0 >= DIM) {
    __syncthreads(); // all waves done with ring reads before gsm reuse
#pragma unroll
    for (int mi = 0; mi < 2; mi++) {
      const int s = wm + mi * 16 + quad * 4;
#pragma unroll
      for (int ni = 0; ni < 4; ni++) {
        const int d = wn + ni * 16 + ln;
        const float bv = bias[n0 + d];
#pragma unroll
        for (int r = 0; r < 4; r++)
          gsm[d * 72 + s + r] = f2b(acc[mi][ni][r] + bv);
      }
    }
    __syncthreads();
    const int d0 = n0 - DIM, bb = m0 >> 11, s0l = m0 & (SS - 1);
#pragma unroll
    for (int t = 0; t < 4; ++t) {
      int idx = tid + t * 256;
      int dr = idx >> 3, cs = (idx & 7) * 8;
      short8 v = *(const short8*)(gsm + dr * 72 + cs);
      *(short8*)(vtOut + (size_t)(bb * DIM + d0 + dr) * SS + s0l + cs) = v;
    }
    return;
  }

#pragma unroll
  for (int mi = 0; mi < 2; mi++) {
    const int row = m0 + wm + mi * 16 + quad * 4;
#pragma unroll
    for (int ni = 0; ni < 4; ni++) {
      const int col = n0 + wn + ni * 16 + ln;
      const float bv = bias[col];
#pragma unroll
      for (int r = 0; r < 4; r++) {
        float v = (acc[mi][ni][r] + bv) * scale;
        size_t o = (size_t)(row + r) * ldout + col;
        if (outF) outF[o] = v;
        if (outB) outB[o] = f2b(v);
      }
    }
  }
}

__global__ __launch_bounds__(256, 4) void gemm_lds(const unsigned short* __restrict__ A,
                                                   const unsigned short* __restrict__ WT,
                                                   const float* __restrict__ bias,
                                                   float* __restrict__ outF,
                                                   unsigned short* __restrict__ outB,
                                                   unsigned short* __restrict__ vtOut,
                                                   int N, int K, int lda, int ldout,
                                                   float scale, int nblk) {
  __shared__ unsigned short gsm[18432]; // 36864 B: ring 3x(A 4KB + B 8KB)
  gemm_body(A, WT, bias, outF, outB, vtOut, N, K, lda, ldout, scale, nblk,
            blockIdx.x, gsm);
}

// Fused stage-2 + Q-path: blocks 0..2047 = stage-2 (N=2048, K=128, fused
// V-transpose), 2048..3071 = Q-path (N=1024, K=256, scale baked in).
__global__ __launch_bounds__(256, 4) void gemm_s2q(
    const unsigned short* __restrict__ kvqlat, const unsigned short* __restrict__ wkvuT,
    const unsigned short* __restrict__ wquT, const float* __restrict__ b_kvu,
    const float* __restrict__ b_qu, unsigned short* __restrict__ kvup,
    unsigned short* __restrict__ VT, unsigned short* __restrict__ Qbuf) {
  __shared__ unsigned short gsm[18432];
  if (blockIdx.x < 2048)
    gemm_body(kvqlat, wkvuT, b_kvu, nullptr, kvup, VT, 2 * DIM, LAT, NCAT,
              2 * DIM, 1.0f, 2048, blockIdx.x, gsm);
  else
    gemm_body(kvqlat + LAT, wquT, b_qu, nullptr, Qbuf, nullptr, DIM, QR, NCAT,
              DIM, SCALE_LOG2E, 1024, blockIdx.x - 2048, gsm);
}

// MFMA flash attention (R11 EXACT — last known good, 81.3 us measured).
// Sequential streams, antidiagonal pairing (tA=pair, tB=31-pair; uniform
// 33 units), 1024 blocks = 4/CU, XCD-affinity decode (K/V L2-resident,
// FETCH ~25 MB), XOR swizzle (conflicts 2.2e6), cvt_pk P-packing.
// NOTE: merged dual-stream variants (R12/R13) produced bit-identical
// deterministic absmax failures across two different staging schemes —
// quarantined pending isolation; do not re-attempt without disasm.
__global__ __launch_bounds__(256, 4) void attn_mfma(const unsigned short* __restrict__ Qb,
                                                    const unsigned short* __restrict__ KVb,
                                                    const unsigned short* __restrict__ VTb,
                                                    unsigned short* __restrict__ ctxB) {
  __shared__ unsigned short smem[12288]; // 24576 B
  unsigned short* Ks = smem;             // [64 key][64 d] swz
  unsigned short* Vts = smem + 4096;     // [64 d][64 key] swz
  unsigned short* Ps = smem + 8192;      // 4 waves x [16 q][64 key] swz
  const int tid = threadIdx.x;
  const int wave = tid >> 6, lane = tid & 63;
  const int ln = lane & 15, quad = lane >> 4;
  // XCD-affinity decode (all 16 pair-blocks of one (b,h) on one XCD)
  const int hw = blockIdx.x;              // 0..1023
  const int xcd = hw & 7, slot = hw >> 3; // slot 0..127
  const int grp = xcd * 8 + (slot >> 4);  // 0..63 = (b,h) group
  const int pair = slot & 15;             // 0..15
  const int h = grp & 15, b = grp >> 4;
  const int tA = pair, tB = 31 - pair;    // 64-row q-tile indices, tB > tA
  const int s0A = tA * 64, s0B = tB * 64;
  const int ktmaxB = tB;                  // inclusive
  const int qminA = s0A + wave * 16, qmaxA = qminA + 15;
  const int qminB = s0B + wave * 16, qmaxB = qminB + 15;

  short8 qfA[2], qfB[2]; // B-operand: rows = q
  {
    const unsigned short* qa =
        Qb + (size_t)(b * SS + s0A + wave * 16 + ln) * DIM + h * HD + quad * 8;
    qfA[0] = *(const short8*)qa;
    qfA[1] = *(const short8*)(qa + 32);
    const unsigned short* qb2 =
        Qb + (size_t)(b * SS + s0B + wave * 16 + ln) * DIM + h * HD + quad * 8;
    qfB[0] = *(const short8*)qb2;
    qfB[1] = *(const short8*)(qb2 + 32);
  }

  f32x4 ocA[4], ocB[4]; // PV acc: row q=quad*4+r, col d=dt*16+ln
  float lpA = 0.f, lpB = 0.f;
#pragma unroll
  for (int i = 0; i < 4; i++) {
    ocA[i] = (f32x4){0.f, 0.f, 0.f, 0.f};
    ocB[i] = (f32x4){0.f, 0.f, 0.f, 0.f};
  }

  unsigned short* Pw = Ps + wave * (16 * 64);
  const int swz = (ln & 7) << 3; // read-side XOR (shorts); row&7 == ln&7

  const int srow = tid >> 3, sc8 = (tid & 7) * 8; // 32 rows per shot
  const int ssc = sc8 ^ ((srow & 7) << 3);        // write-side XOR (shorts)

  const unsigned short* kptr =
      KVb + (size_t)(b * SS + srow) * (2 * DIM) + h * HD + sc8;
  const unsigned short* vptr = VTb + (size_t)(b * DIM + h * HD + srow) * SS + sc8;
  const size_t kstep = (size_t)64 * 2 * DIM;
  const size_t krow32 = (size_t)32 * 2 * DIM;
  const size_t vrow32 = (size_t)32 * SS;

  short8 kreg0 = *(const short8*)kptr;
  short8 kreg1 = *(const short8*)(kptr + krow32);
  short8 vreg0 = *(const short8*)vptr;
  short8 vreg1 = *(const short8*)(vptr + vrow32);

  for (int kt = 0; kt <= ktmaxB; ++kt) {
    __syncthreads(); // prior-iter LDS readers done
    *(short8*)(Ks + srow * 64 + ssc) = kreg0;
    *(short8*)(Ks + (srow + 32) * 64 + ssc) = kreg1;
    *(short8*)(Vts + srow * 64 + ssc) = vreg0;
    *(short8*)(Vts + (srow + 32) * 64 + ssc) = vreg1;
    __syncthreads();
    if (kt < ktmaxB) { // prefetch next K/V tile (overlaps compute)
      kptr += kstep; vptr += 64;
      kreg0 = *(const short8*)kptr;
      kreg1 = *(const short8*)(kptr + krow32);
      vreg0 = *(const short8*)vptr;
      vreg1 = *(const short8*)(vptr + vrow32);
    }

    const int k0g = kt * 64;

    auto stream = [&](const short8* qf, f32x4* oc, float& lp, const int qminw,
                      const int qmaxw) {
      if (k0g > qmaxw) return; // whole tile masked for this wave (wave-uniform)
      const bool needmask = (k0g + 63 > qminw);

      f32x4 sacc[4]; // S^T: nt -> keys k0g+nt*16+quad*4+r, col q=ln
#pragma unroll
      for (int nt = 0; nt < 4; nt++) sacc[nt] = (f32x4){0.f, 0.f, 0.f, 0.f};
      __builtin_amdgcn_s_setprio(1);
#pragma unroll
      for (int kc = 0; kc < 2; kc++) {
        const int rc = (kc * 32 + quad * 8) ^ swz;
#pragma unroll
        for (int nt = 0; nt < 4; nt++) {
          if (k0g + nt * 16 > qmaxw) continue; // strip fully masked
          short8 kfrag = *(const short8*)(Ks + (nt * 16 + ln) * 64 + rc);
          sacc[nt] =
              __builtin_amdgcn_mfma_f32_16x16x32_bf16(kfrag, qf[kc], sacc[nt], 0, 0, 0);
        }
      }
      __builtin_amdgcn_s_setprio(0);

      // Fixed-max softmax (scale pre-baked into Q): interior path has no
      // per-element masking VALU; P packed via v_cvt_pk_bf16_f32.
      const int qg = qminw + ln; // this thread's q column (global)
      float lt = 0.f;
      if (!needmask) {
#pragma unroll
        for (int nt = 0; nt < 4; nt++) {
          float p0 = __builtin_exp2f(sacc[nt][0]);
          float p1 = __builtin_exp2f(sacc[nt][1]);
          float p2 = __builtin_exp2f(sacc[nt][2]);
          float p3 = __builtin_exp2f(sacc[nt][3]);
          uint2 pw;
          pw.x = cvtpk_bf16(p0, p1);
          pw.y = cvtpk_bf16(p2, p3);
          *(uint2*)(Pw + ln * 64 + ((nt * 16 + quad * 4) ^ swz)) = pw;
          lt += (p0 + p1) + (p2 + p3);
        }
      } else {
#pragma unroll
        for (int nt = 0; nt < 4; nt++) {
          const int base = k0g + nt * 16 + quad * 4;
          float pe[4];
#pragma unroll
          for (int r = 0; r < 4; r++) {
            float p = __builtin_exp2f(sacc[nt][r]);
            if (base + r > qg) p = 0.f;
            pe[r] = p;
          }
          uint2 pw;
          pw.x = cvtpk_bf16(pe[0], pe[1]);
          pw.y = cvtpk_bf16(pe[2], pe[3]);
          *(uint2*)(Pw + ln * 64 + ((nt * 16 + quad * 4) ^ swz)) = pw;
          lt += (pe[0] + pe[1]) + (pe[2] + pe[3]);
        }
      }
      lp += lt;

      __builtin_amdgcn_s_setprio(1);
#pragma unroll
      for (int kc = 0; kc < 2; kc++) {
        if (k0g + kc * 32 > qmaxw) continue; // P chunk all zero
        const int rc = (kc * 32 + quad * 8) ^ swz;
        short8 pfrag = *(const short8*)(Pw + ln * 64 + rc);
#pragma unroll
        for (int dt = 0; dt < 4; dt++) {
          short8 vfrag = *(const short8*)(Vts + (dt * 16 + ln) * 64 + rc);
          oc[dt] =
              __builtin_amdgcn_mfma_f32_16x16x32_bf16(pfrag, vfrag, oc[dt], 0, 0, 0);
        }
      }
      __builtin_amdgcn_s_setprio(0);
    };

    stream(qfA, ocA, lpA, qminA, qmaxA);
    stream(qfB, ocB, lpB, qminB, qmaxB);
  }

  // Denominators: reduce across the 4 quads, broadcast to owned rows.
  lpA += __shfl_xor(lpA, 16, 64);
  lpA += __shfl_xor(lpA, 32, 64);
  lpB += __shfl_xor(lpB, 16, 64);
  lpB += __shfl_xor(lpB, 32, 64);
  float liA[4], liB[4];
#pragma unroll
  for (int r = 0; r < 4; r++) {
    liA[r] = 1.f / __shfl(lpA, quad * 4 + r, 64);
    liB[r] = 1.f / __shfl(lpB, quad * 4 + r, 64);
  }

  // Epilogue: normalize, stage each 64x64 tile through smem, 16B stores.
  __syncthreads();
#pragma unroll
  for (int r = 0; r < 4; r++) {
#pragma unroll
    for (int dt = 0; dt < 4; dt++)
      smem[(wave * 16 + quad * 4 + r) * 72 + dt * 16 + ln] = f2b(ocA[dt][r] * liA[r]);
  }
  __syncthreads();
#pragma unroll
  for (int t = 0; t < 2; ++t) {
    int idx = tid + t * 256;
    int row = idx >> 3, c = idx & 7;
    short8 v = *(const short8*)(smem + row * 72 + c * 8);
    *(short8*)(ctxB + (size_t)(b * SS + s0A + row) * DIM + h * HD + c * 8) = v;
  }
  __syncthreads();
#pragma unroll
  for (int r = 0; r < 4; r++) {
#pragma unroll
    for (int dt = 0; dt < 4; dt++)
      smem[(wave * 16 + quad * 4 + r) * 72 + dt * 16 + ln] = f2b(ocB[dt][r] * liB[r]);
  }
  __syncthreads();
#pragma unroll
  for (int t = 0; t < 2; ++t) {
    int idx = tid + t * 256;
    int row = idx >> 3, c = idx & 7;
    short8 v = *(const short8*)(smem + row * 72 + c * 8);
    *(short8*)(ctxB + (size_t)(b * SS + s0B + row) * DIM + h * HD + c * 8) = v;
  }
}

extern "C" void kernel_launch(void* const* d_in, const int* in_sizes, int n_in,
                              void* d_out, int out_size, void* d_ws, size_t ws_size,
                              hipStream_t stream) {
  const float* x     = (const float*)d_in[0];
  const float* w_kvc = (const float*)d_in[2];
  const float* b_kvc = (const float*)d_in[3];
  const float* w_kvu = (const float*)d_in[4];
  const float* b_kvu = (const float*)d_in[5];
  const float* w_qc  = (const float*)d_in[6];
  const float* b_qc  = (const float*)d_in[7];
  const float* w_qu  = (const float*)d_in[8];
  const float* b_qu  = (const float*)d_in[9];
  const float* w_o   = (const float*)d_in[10];
  const float* b_o   = (const float*)d_in[11];
  float* out = (float*)d_out;

  unsigned short* xb     = (unsigned short*)d_ws;          // [BS][DIM]; reused as VT
  unsigned short* wcatT  = xb + (size_t)BS * DIM;          // [NCAT][DIM]
  unsigned short* wkvuT  = wcatT + (size_t)NCAT * DIM;     // [2*DIM][LAT]
  unsigned short* wquT   = wkvuT + (size_t)LAT * 2 * DIM;  // [DIM][QR]
  unsigned short* woT    = wquT + (size_t)QR * DIM;        // [DIM][DIM]
  unsigned short* kvqlat = woT + (size_t)DIM * DIM;        // [BS][NCAT] (kv | q)
  unsigned short* kvup   = kvqlat + (size_t)BS * NCAT;     // [BS][2*DIM] (K | dead V)
  unsigned short* Qbuf   = kvup + (size_t)BS * 2 * DIM;    // [BS][DIM]
  unsigned short* ctx    = Qbuf + (size_t)BS * DIM;        // [BS][DIM]
  float* bias_cat        = (float*)(ctx + (size_t)BS * DIM); // [NCAT]

  // fused convert + weight prep (one launch)
  cvt_prep<<<8673, 256, 0, stream>>>(x, xb, w_kvc, w_qc, w_kvu, w_qu, w_o,
                                     b_kvc, b_qc, wcatT, wkvuT, wquT, woT,
                                     bias_cat);

  // stage-1: [kvlat | qlat] = x @ [w_kvc | w_qc]   (8192x384x1024), 384 blocks
  gemm_lds<<<384, 256, 0, stream>>>(xb, wcatT, bias_cat, nullptr, kvqlat,
                                    nullptr, NCAT, DIM, DIM, NCAT, 1.0f, 384);
  unsigned short* VT = xb; // xb dead after stage-1
  // fused stage-2 (8192x2048x128, V written transposed to VT) + Q-path
  // (8192x1024x256, softmax scale baked in): 3072 blocks
  gemm_s2q<<<3072, 256, 0, stream>>>(kvqlat, wkvuT, wquT, b_kvu, b_qu, kvup,
                                     VT, Qbuf);
  attn_mfma<<<1024, 256, 0, stream>>>(Qbuf, kvup, VT, ctx);
  // O-proj (8192x1024x1024), 1024 blocks
  gemm_lds<<<1024, 256, 0, stream>>>(ctx, woT, b_o, out, nullptr, nullptr,
                                     DIM, DIM, DIM, DIM, 1.0f, 1024);
}